// Round 4
// baseline (670.598 us; speedup 1.0000x reference)
//
#include <hip/hip_runtime.h>

// GCN 2-layer forward on gfx950 — defensive build.
// Dtypes of float tensors (fp32 vs bf16) and edge_index (int32 vs int64)
// are DETECTED on device; every dynamic index is clamped so GPU memory
// faults from these kernels are structurally impossible.

typedef unsigned int u32;
typedef unsigned short u16;
typedef __bf16 bf16x8 __attribute__((ext_vector_type(8)));
typedef float f32x4 __attribute__((ext_vector_type(4)));

#define C_IN 512
#define C_HID 512
#define C_OUT 40

__device__ __forceinline__ float bf2f(u16 u) {
    u32 x = ((u32)u) << 16;
    return __builtin_bit_cast(float, x);
}
__device__ __forceinline__ u16 f2bf(float f) {
    u32 x = __builtin_bit_cast(u32, f);
    x += 0x7fffu + ((x >> 16) & 1u);   // RNE
    return (u16)(x >> 16);
}
__host__ __device__ __forceinline__ int imin(int a, int b) { return a < b ? a : b; }
__host__ __device__ __forceinline__ int imax(int a, int b) { return a > b ? a : b; }

// ---------------- dtype detection ----------------
// flags[0] = int32 step per typed edge element (1 = int32 data, 2 = int64 data)
// flags[1] = 1 if float tensors are bf16-packed, 0 if fp32
__global__ void k_detect(const u32* __restrict__ x32, const int* __restrict__ ei,
                         int* flags) {
    if (blockIdx.x || threadIdx.x) return;
    int zeros = 0;
    for (int k = 0; k < 128; ++k) zeros += (ei[2 * k + 1] == 0);
    int votes = 0;
    for (int i = 0; i < 128; ++i) {
        u32 e = (x32[i] >> 7) & 0xff;          // bf16 exponent field if packed
        votes += (e >= 110 && e <= 133);
    }
    flags[0] = (zeros == 128) ? 2 : 1;
    flags[1] = (votes >= 96) ? 1 : 0;
}

// ---------------- graph preprocessing ----------------

__global__ void k_init(int* deg, int* cursor, int n) {
    int i = blockIdx.x * 256 + threadIdx.x;
    if (i < n) { deg[i] = 1; cursor[i] = 0; }   // self-loop
}

__global__ void k_deg(const int* __restrict__ ei, const int* __restrict__ flags,
                      int* deg, int E, int ecap, int n) {
    int e = blockIdx.x * 256 + threadIdx.x;
    if (e >= E) return;
    int st = flags[0];
    int cap = ecap * st - 1;
    u32 d = (u32)ei[imin((E + e) * st, cap)];
    if (d < (u32)n) atomicAdd(&deg[d], 1);
}

__global__ void k_dinv(const int* __restrict__ deg, float* dinv, int n) {
    int i = blockIdx.x * 256 + threadIdx.x;
    if (i < n) dinv[i] = rsqrtf((float)imax(deg[i], 1));
}

// exclusive scan of (deg[i]-1) -> offs
__global__ void k_scanA(const int* __restrict__ deg, int* bsum, int n) {
    __shared__ int sh[256];
    int i = blockIdx.x * 256 + threadIdx.x;
    sh[threadIdx.x] = (i < n) ? deg[i] - 1 : 0;
    __syncthreads();
    for (int d = 128; d > 0; d >>= 1) {
        if (threadIdx.x < d) sh[threadIdx.x] += sh[threadIdx.x + d];
        __syncthreads();
    }
    if (threadIdx.x == 0) bsum[blockIdx.x] = sh[0];
}

__global__ void k_scanB(int* bsum, int nb, int* offs, int n) {
    if (threadIdx.x == 0 && blockIdx.x == 0) {
        int run = 0;
        for (int b = 0; b < nb; ++b) { int t = bsum[b]; bsum[b] = run; run += t; }
        offs[n] = run;
    }
}

__global__ void k_scanC(const int* __restrict__ deg, const int* __restrict__ bsum,
                        int* offs, int n) {
    __shared__ int sh[256];
    int t = threadIdx.x;
    int i = blockIdx.x * 256 + t;
    int v = (i < n) ? deg[i] - 1 : 0;
    sh[t] = v;
    __syncthreads();
    for (int d = 1; d < 256; d <<= 1) {
        int add = (t >= d) ? sh[t - d] : 0;
        __syncthreads();
        sh[t] += add;
        __syncthreads();
    }
    if (i < n) offs[i] = bsum[blockIdx.x] + sh[t] - v;
}

__global__ void k_sort(const int* __restrict__ ei, const int* __restrict__ flags,
                       const int* __restrict__ offs, int* cursor, int* csr,
                       int E, int ecap, int n) {
    int e = blockIdx.x * 256 + threadIdx.x;
    if (e >= E) return;
    int st = flags[0];
    int cap = ecap * st - 1;
    u32 d = (u32)ei[imin((E + e) * st, cap)];
    u32 s = (u32)ei[imin(e * st, cap)];
    if (d < (u32)n && s < (u32)n) {
        int pos = offs[d] + atomicAdd(&cursor[(int)d], 1);
        if ((u32)pos < (u32)E) csr[pos] = (int)s;
    }
}

// ---------------- conversions into known-layout ws buffers ----------------

__device__ __forceinline__ float ldf(const void* p, int i, int isbf) {
    return isbf ? bf2f(((const u16*)p)[i]) : ((const float*)p)[i];
}

__global__ void k_convx(const void* __restrict__ x, const int* __restrict__ flags,
                        u16* __restrict__ out, int nelem) {
    int i = blockIdx.x * 256 + threadIdx.x;
    if (i >= nelem) return;
    int isbf = flags[1];
    out[i] = isbf ? ((const u16*)x)[i] : f2bf(((const float*)x)[i]);
}

// W1[512][512] -> W1t[n][k] bf16
__global__ void k_w1t(const void* __restrict__ W, const int* __restrict__ flags,
                      u16* __restrict__ out) {
    int id = blockIdx.x * 256 + threadIdx.x;   // 512*512
    int n = id >> 9, k = id & 511;
    out[n * 512 + k] = f2bf(ldf(W, k * 512 + n, flags[1]));
}

// W2[512][40] -> W2t[64][512] bf16, rows 40..63 zero
__global__ void k_w2t(const void* __restrict__ W, const int* __restrict__ flags,
                      u16* __restrict__ out) {
    int id = blockIdx.x * 256 + threadIdx.x;   // 64*512
    int n = id >> 9, k = id & 511;
    out[id] = (n < C_OUT) ? f2bf(ldf(W, k * C_OUT + n, flags[1])) : (u16)0;
}

__global__ void k_bias(const void* __restrict__ b1, const void* __restrict__ b2,
                       const int* __restrict__ flags, float* __restrict__ b1f,
                       float* __restrict__ b2f) {
    int i = threadIdx.x + blockIdx.x * 256;
    int isbf = flags[1];
    if (i < C_HID) b1f[i] = ldf(b1, i, isbf);
    if (i < C_OUT) b2f[i] = ldf(b2, i, isbf);
}

// ---------------- MFMA GEMM: C = A (MxK) * Bt^T, bf16, row-major along K ------------
// verified layouts (learn_hip m89/m91/m120):
//   A frag: A[m=lane&15][k=(lane>>4)*8+j]; B frag == Bt[n=lane&15][k]
//   C/D: row=(lane>>4)*4+reg, col=lane&15
template <bool OUT_BF16>
__global__ __launch_bounds__(256) void k_gemm_bt(
    const u16* __restrict__ A, const u16* __restrict__ Bt, void* __restrict__ Cout,
    int M, int K, int Ncols, int ldc) {
    __shared__ __align__(16) u16 As[64 * 32];
    __shared__ __align__(16) u16 Bs[64 * 32];
    int tid = threadIdx.x;
    int wave = tid >> 6, lane = tid & 63;
    int quad = lane >> 4, lrow = lane & 15;
    int row0 = blockIdx.x * 64;
    int n0 = blockIdx.y * 64;
    int srow = tid >> 2;
    int skc = (tid & 3) * 8;

    f32x4 acc[4] = {};
    int kTiles = K >> 5;
    for (int kt = 0; kt < kTiles; ++kt) {
        int k0 = kt * 32;
        uint4 av = make_uint4(0, 0, 0, 0);
        int gr = row0 + srow;
        if (gr < M) av = *(const uint4*)(A + (size_t)gr * K + k0 + skc);
        uint4 bv = *(const uint4*)(Bt + (size_t)(n0 + srow) * K + k0 + skc);
        __syncthreads();
        *(uint4*)(As + srow * 32 + skc) = av;
        *(uint4*)(Bs + srow * 32 + skc) = bv;
        __syncthreads();
        bf16x8 af = *(const bf16x8*)(As + (wave * 16 + lrow) * 32 + quad * 8);
#pragma unroll
        for (int t = 0; t < 4; ++t) {
            bf16x8 bfr = *(const bf16x8*)(Bs + (t * 16 + lrow) * 32 + quad * 8);
            acc[t] = __builtin_amdgcn_mfma_f32_16x16x32_bf16(af, bfr, acc[t], 0, 0, 0);
        }
    }
#pragma unroll
    for (int t = 0; t < 4; ++t) {
#pragma unroll
        for (int r = 0; r < 4; ++r) {
            int row = wave * 16 + quad * 4 + r;
            int col = t * 16 + lrow;
            int gr = row0 + row, gc = n0 + col;
            if (gr < M && gc < Ncols) {
                float val = acc[t][r];
                if (OUT_BF16) ((u16*)Cout)[(size_t)gr * ldc + gc] = f2bf(val);
                else ((float*)Cout)[(size_t)gr * ldc + gc] = val;
            }
        }
    }
}

// ---------------- agg1: hagg = ReLU(Anorm*h + b1), bf16 in/out ----------------
__global__ __launch_bounds__(256) void k_agg1(
    const u16* __restrict__ h, const int* __restrict__ csr, const int* __restrict__ offs,
    const float* __restrict__ dinv, const float* __restrict__ b1f,
    u16* __restrict__ out, int n, int Etot) {
    int v = blockIdx.x;
    if (v >= n) return;
    int t = threadIdx.x;
    float dv = dinv[v];
    u32 hv = *(const u32*)(h + (size_t)v * C_HID + 2 * t);
    float a0 = dv * dv * bf2f((u16)hv);
    float a1 = dv * dv * bf2f((u16)(hv >> 16));
    int e0 = imax(0, imin(offs[v], Etot));
    int e1 = imax(e0, imin(offs[v + 1], Etot));
    for (int e = e0; e < e1; ++e) {
        u32 s = (u32)csr[e];
        if (s < (u32)n) {
            float w = dv * dinv[s];
            u32 hs = *(const u32*)(h + (size_t)s * C_HID + 2 * t);
            a0 += w * bf2f((u16)hs);
            a1 += w * bf2f((u16)(hs >> 16));
        }
    }
    a0 = fmaxf(a0 + b1f[2 * t], 0.f);
    a1 = fmaxf(a1 + b1f[2 * t + 1], 0.f);
    u32 o = (u32)f2bf(a0) | ((u32)f2bf(a1) << 16);
    *(u32*)(out + (size_t)v * C_HID + 2 * t) = o;
}

// ---------------- agg2 + bias + log_softmax; adaptive-width store ----------------
__global__ __launch_bounds__(256) void k_agg2(
    const float* __restrict__ h2, const int* __restrict__ csr, const int* __restrict__ offs,
    const float* __restrict__ dinv, const float* __restrict__ b2f,
    const int* __restrict__ flags, void* __restrict__ out, int n, int Etot) {
    int wave = threadIdx.x >> 6, lane = threadIdx.x & 63;
    int v = blockIdx.x * 4 + wave;
    if (v >= n) return;
    float dv = dinv[v];
    float acc = 0.f;
    if (lane < C_OUT) acc = dv * dv * h2[(size_t)v * C_OUT + lane];
    int e0 = imax(0, imin(offs[v], Etot));
    int e1 = imax(e0, imin(offs[v + 1], Etot));
    for (int e = e0; e < e1; ++e) {
        u32 s = (u32)csr[e];
        if (s < (u32)n && lane < C_OUT) acc += dv * dinv[s] * h2[(size_t)s * C_OUT + lane];
    }
    if (lane < C_OUT) acc += b2f[lane];
    float m = (lane < C_OUT) ? acc : -1e30f;
    for (int off = 32; off > 0; off >>= 1) m = fmaxf(m, __shfl_xor(m, off));
    float ex = (lane < C_OUT) ? expf(acc - m) : 0.f;
    float sum = ex;
    for (int off = 32; off > 0; off >>= 1) sum += __shfl_xor(sum, off);
    if (lane < C_OUT) {
        float r = acc - m - logf(sum);
        if (flags[1]) ((u16*)out)[(size_t)v * C_OUT + lane] = f2bf(r);
        else ((float*)out)[(size_t)v * C_OUT + lane] = r;
    }
}

// ---------------- launch ----------------

extern "C" void kernel_launch(void* const* d_in, const int* in_sizes, int n_in,
                              void* d_out, int out_size, void* d_ws, size_t ws_size,
                              hipStream_t stream) {
    const void* x = d_in[0];
    const int* ei = (const int*)d_in[1];
    const void* W1 = d_in[2];
    const void* b1 = d_in[3];
    const void* W2 = d_in[4];
    const void* b2 = d_in[5];

    const int N = out_size / C_OUT;          // output rows (50000)
    const int Mx = in_sizes[0] / C_IN;       // x rows
    const int M = (N < Mx) ? N : Mx;
    const int ECAP = in_sizes[1];            // typed edge elements (2E)
    const int E = ECAP / 2;

    char* p = (char*)d_ws;
    size_t used = 0;
    auto carve = [&](size_t bytes) -> void* {
        void* r = (void*)p;
        size_t b = (bytes + 255) & ~(size_t)255;
        p += b; used += b;
        return r;
    };
    int* flags = (int*)carve(256);
    int* deg = (int*)carve((size_t)N * 4);
    int* cursor = (int*)carve((size_t)N * 4);
    float* dinv = (float*)carve((size_t)N * 4);
    int* offs = (int*)carve((size_t)(N + 1) * 4);
    int* bsum = (int*)carve(8192);
    int* csr = (int*)carve((size_t)E * 4);
    u16* w1t = (u16*)carve((size_t)C_HID * C_IN * 2);
    u16* w2t = (u16*)carve((size_t)64 * C_HID * 2);
    float* b1f = (float*)carve(C_HID * 4);
    float* b2f = (float*)carve(256);
    u16* bufA = (u16*)carve((size_t)N * C_HID * 2);   // xbf, then hagg
    u16* bufB = (u16*)carve((size_t)N * C_HID * 2);   // hbf, then h2 (fp32, 8MB)
    if (used > ws_size) return;   // bail -> loud absmax failure, no fault

    u16* xbf = bufA;
    u16* hbf = bufB;
    u16* hagg = bufA;
    float* h2 = (float*)bufB;

    const int NB = (N + 255) / 256;
    const int EB = (E + 255) / 256;

    k_detect<<<1, 64, 0, stream>>>((const u32*)x, ei, flags);

    k_init<<<NB, 256, 0, stream>>>(deg, cursor, N);
    k_deg<<<EB, 256, 0, stream>>>(ei, flags, deg, E, ECAP, N);
    k_dinv<<<NB, 256, 0, stream>>>(deg, dinv, N);
    k_scanA<<<NB, 256, 0, stream>>>(deg, bsum, N);
    k_scanB<<<1, 64, 0, stream>>>(bsum, NB, offs, N);
    k_scanC<<<NB, 256, 0, stream>>>(deg, bsum, offs, N);
    k_sort<<<EB, 256, 0, stream>>>(ei, flags, offs, cursor, csr, E, ECAP, N);

    k_convx<<<(M * C_IN + 255) / 256, 256, 0, stream>>>(x, flags, xbf, M * C_IN);
    k_w1t<<<(C_IN * C_HID) / 256, 256, 0, stream>>>(W1, flags, w1t);
    k_w2t<<<(64 * C_HID) / 256, 256, 0, stream>>>(W2, flags, w2t);
    k_bias<<<2, 256, 0, stream>>>(b1, b2, flags, b1f, b2f);

    dim3 g1((N + 63) / 64, C_HID / 64);
    k_gemm_bt<true><<<g1, 256, 0, stream>>>(xbf, w1t, (void*)hbf, M, C_IN, C_HID, C_HID);

    k_agg1<<<N, 256, 0, stream>>>(hbf, csr, offs, dinv, b1f, hagg, N, E);

    dim3 g2((N + 63) / 64, 1);
    k_gemm_bt<false><<<g2, 256, 0, stream>>>(hagg, w2t, (void*)h2, N, C_HID, C_OUT, C_OUT);

    k_agg2<<<(N + 3) / 4, 256, 0, stream>>>(h2, csr, offs, dinv, b2f, flags, d_out, N, E);
}

// Round 5
// 558.019 us; speedup vs baseline: 1.2017x; 1.2017x over previous
//
#include <hip/hip_runtime.h>

// GCN 2-layer forward on gfx950.
// R5: aggregation kernels rewritten for memory-level parallelism:
//     wave-per-node, shfl-broadcast neighbor indices, 16B/lane gathers, unroll-4.

typedef unsigned int u32;
typedef unsigned short u16;
typedef __bf16 bf16x8 __attribute__((ext_vector_type(8)));
typedef float f32x4 __attribute__((ext_vector_type(4)));

#define C_IN 512
#define C_HID 512
#define C_OUT 40

__device__ __forceinline__ float bf2f(u16 u) {
    u32 x = ((u32)u) << 16;
    return __builtin_bit_cast(float, x);
}
__device__ __forceinline__ u16 f2bf(float f) {
    u32 x = __builtin_bit_cast(u32, f);
    x += 0x7fffu + ((x >> 16) & 1u);   // RNE
    return (u16)(x >> 16);
}
__host__ __device__ __forceinline__ int imin(int a, int b) { return a < b ? a : b; }
__host__ __device__ __forceinline__ int imax(int a, int b) { return a > b ? a : b; }

// ---------------- dtype detection ----------------
__global__ void k_detect(const u32* __restrict__ x32, const int* __restrict__ ei,
                         int* flags) {
    if (blockIdx.x || threadIdx.x) return;
    int zeros = 0;
    for (int k = 0; k < 128; ++k) zeros += (ei[2 * k + 1] == 0);
    int votes = 0;
    for (int i = 0; i < 128; ++i) {
        u32 e = (x32[i] >> 7) & 0xff;
        votes += (e >= 110 && e <= 133);
    }
    flags[0] = (zeros == 128) ? 2 : 1;   // int32 step per edge element
    flags[1] = (votes >= 96) ? 1 : 0;    // floats bf16-packed?
}

// ---------------- graph preprocessing ----------------

__global__ void k_init(int* deg, int* cursor, int n) {
    int i = blockIdx.x * 256 + threadIdx.x;
    if (i < n) { deg[i] = 1; cursor[i] = 0; }
}

__global__ void k_deg(const int* __restrict__ ei, const int* __restrict__ flags,
                      int* deg, int E, int ecap, int n) {
    int e = blockIdx.x * 256 + threadIdx.x;
    if (e >= E) return;
    int st = flags[0];
    int cap = ecap * st - 1;
    u32 d = (u32)ei[imin((E + e) * st, cap)];
    if (d < (u32)n) atomicAdd(&deg[d], 1);
}

__global__ void k_dinv(const int* __restrict__ deg, float* dinv, int n) {
    int i = blockIdx.x * 256 + threadIdx.x;
    if (i < n) dinv[i] = rsqrtf((float)imax(deg[i], 1));
}

__global__ void k_scanA(const int* __restrict__ deg, int* bsum, int n) {
    __shared__ int sh[256];
    int i = blockIdx.x * 256 + threadIdx.x;
    sh[threadIdx.x] = (i < n) ? deg[i] - 1 : 0;
    __syncthreads();
    for (int d = 128; d > 0; d >>= 1) {
        if (threadIdx.x < d) sh[threadIdx.x] += sh[threadIdx.x + d];
        __syncthreads();
    }
    if (threadIdx.x == 0) bsum[blockIdx.x] = sh[0];
}

__global__ void k_scanB(int* bsum, int nb, int* offs, int n) {
    if (threadIdx.x == 0 && blockIdx.x == 0) {
        int run = 0;
        for (int b = 0; b < nb; ++b) { int t = bsum[b]; bsum[b] = run; run += t; }
        offs[n] = run;
    }
}

__global__ void k_scanC(const int* __restrict__ deg, const int* __restrict__ bsum,
                        int* offs, int n) {
    __shared__ int sh[256];
    int t = threadIdx.x;
    int i = blockIdx.x * 256 + t;
    int v = (i < n) ? deg[i] - 1 : 0;
    sh[t] = v;
    __syncthreads();
    for (int d = 1; d < 256; d <<= 1) {
        int add = (t >= d) ? sh[t - d] : 0;
        __syncthreads();
        sh[t] += add;
        __syncthreads();
    }
    if (i < n) offs[i] = bsum[blockIdx.x] + sh[t] - v;
}

__global__ void k_sort(const int* __restrict__ ei, const int* __restrict__ flags,
                       const int* __restrict__ offs, int* cursor, int* csr,
                       int E, int ecap, int n) {
    int e = blockIdx.x * 256 + threadIdx.x;
    if (e >= E) return;
    int st = flags[0];
    int cap = ecap * st - 1;
    u32 d = (u32)ei[imin((E + e) * st, cap)];
    u32 s = (u32)ei[imin(e * st, cap)];
    if (d < (u32)n && s < (u32)n) {
        int pos = offs[d] + atomicAdd(&cursor[(int)d], 1);
        if ((u32)pos < (u32)E) csr[pos] = (int)s;
    }
}

// ---------------- conversions ----------------

__device__ __forceinline__ float ldf(const void* p, int i, int isbf) {
    return isbf ? bf2f(((const u16*)p)[i]) : ((const float*)p)[i];
}

__global__ void k_convx(const void* __restrict__ x, const int* __restrict__ flags,
                        u16* __restrict__ out, int nelem) {
    int i = blockIdx.x * 256 + threadIdx.x;
    if (i >= nelem) return;
    int isbf = flags[1];
    out[i] = isbf ? ((const u16*)x)[i] : f2bf(((const float*)x)[i]);
}

__global__ void k_w1t(const void* __restrict__ W, const int* __restrict__ flags,
                      u16* __restrict__ out) {
    int id = blockIdx.x * 256 + threadIdx.x;
    int n = id >> 9, k = id & 511;
    out[n * 512 + k] = f2bf(ldf(W, k * 512 + n, flags[1]));
}

__global__ void k_w2t(const void* __restrict__ W, const int* __restrict__ flags,
                      u16* __restrict__ out) {
    int id = blockIdx.x * 256 + threadIdx.x;
    int n = id >> 9, k = id & 511;
    out[id] = (n < C_OUT) ? f2bf(ldf(W, k * C_OUT + n, flags[1])) : (u16)0;
}

__global__ void k_bias(const void* __restrict__ b1, const void* __restrict__ b2,
                       const int* __restrict__ flags, float* __restrict__ b1f,
                       float* __restrict__ b2f) {
    int i = threadIdx.x + blockIdx.x * 256;
    int isbf = flags[1];
    if (i < C_HID) b1f[i] = ldf(b1, i, isbf);
    if (i < C_OUT) b2f[i] = ldf(b2, i, isbf);
}

// ---------------- MFMA GEMM (unchanged from R4) ----------------
template <bool OUT_BF16>
__global__ __launch_bounds__(256) void k_gemm_bt(
    const u16* __restrict__ A, const u16* __restrict__ Bt, void* __restrict__ Cout,
    int M, int K, int Ncols, int ldc) {
    __shared__ __align__(16) u16 As[64 * 32];
    __shared__ __align__(16) u16 Bs[64 * 32];
    int tid = threadIdx.x;
    int wave = tid >> 6, lane = tid & 63;
    int quad = lane >> 4, lrow = lane & 15;
    int row0 = blockIdx.x * 64;
    int n0 = blockIdx.y * 64;
    int srow = tid >> 2;
    int skc = (tid & 3) * 8;

    f32x4 acc[4] = {};
    int kTiles = K >> 5;
    for (int kt = 0; kt < kTiles; ++kt) {
        int k0 = kt * 32;
        uint4 av = make_uint4(0, 0, 0, 0);
        int gr = row0 + srow;
        if (gr < M) av = *(const uint4*)(A + (size_t)gr * K + k0 + skc);
        uint4 bv = *(const uint4*)(Bt + (size_t)(n0 + srow) * K + k0 + skc);
        __syncthreads();
        *(uint4*)(As + srow * 32 + skc) = av;
        *(uint4*)(Bs + srow * 32 + skc) = bv;
        __syncthreads();
        bf16x8 af = *(const bf16x8*)(As + (wave * 16 + lrow) * 32 + quad * 8);
#pragma unroll
        for (int t = 0; t < 4; ++t) {
            bf16x8 bfr = *(const bf16x8*)(Bs + (t * 16 + lrow) * 32 + quad * 8);
            acc[t] = __builtin_amdgcn_mfma_f32_16x16x32_bf16(af, bfr, acc[t], 0, 0, 0);
        }
    }
#pragma unroll
    for (int t = 0; t < 4; ++t) {
#pragma unroll
        for (int r = 0; r < 4; ++r) {
            int row = wave * 16 + quad * 4 + r;
            int col = t * 16 + lrow;
            int gr = row0 + row, gc = n0 + col;
            if (gr < M && gc < Ncols) {
                float val = acc[t][r];
                if (OUT_BF16) ((u16*)Cout)[(size_t)gr * ldc + gc] = f2bf(val);
                else ((float*)Cout)[(size_t)gr * ldc + gc] = val;
            }
        }
    }
}

// ---------------- agg1: hagg = ReLU(Anorm*h + b1), bf16 in/out ----------------
// wave-per-node; 64 lanes x 8 features (uint4); indices preloaded to lane regs,
// shfl-broadcast (uniform j -> readlane -> SGPR saddr loads), unroll-4 for MLP.

__device__ __forceinline__ void accum8(float* acc, uint4 p, float w) {
    acc[0] += w * bf2f((u16)p.x); acc[1] += w * bf2f((u16)(p.x >> 16));
    acc[2] += w * bf2f((u16)p.y); acc[3] += w * bf2f((u16)(p.y >> 16));
    acc[4] += w * bf2f((u16)p.z); acc[5] += w * bf2f((u16)(p.z >> 16));
    acc[6] += w * bf2f((u16)p.w); acc[7] += w * bf2f((u16)(p.w >> 16));
}

__global__ __launch_bounds__(256) void k_agg1(
    const u16* __restrict__ h, const int* __restrict__ csr, const int* __restrict__ offs,
    const float* __restrict__ dinv, const float* __restrict__ b1f,
    u16* __restrict__ out, int n, int Etot) {
    int wave = threadIdx.x >> 6, lane = threadIdx.x & 63;
    int v = blockIdx.x * 4 + wave;
    if (v >= n) return;   // wave-uniform
    float dv = dinv[v];
    float wself = dv * dv;

    float acc[8];
    uint4 hs = *(const uint4*)(h + (size_t)v * C_HID + lane * 8);
    acc[0] = wself * bf2f((u16)hs.x); acc[1] = wself * bf2f((u16)(hs.x >> 16));
    acc[2] = wself * bf2f((u16)hs.y); acc[3] = wself * bf2f((u16)(hs.y >> 16));
    acc[4] = wself * bf2f((u16)hs.z); acc[5] = wself * bf2f((u16)(hs.z >> 16));
    acc[6] = wself * bf2f((u16)hs.w); acc[7] = wself * bf2f((u16)(hs.w >> 16));

    int e0 = imax(0, imin(offs[v], Etot));
    int e1 = imax(e0, imin(offs[v + 1], Etot));
    for (int base = e0; base < e1; base += 64) {
        int cnt = imin(64, e1 - base);
        int sreg = 0; float wreg = 0.f;
        if (lane < cnt) {
            u32 s = (u32)csr[base + lane];
            s = (s < (u32)n) ? s : 0u;   // clamp (never triggers on valid data)
            sreg = (int)s;
            wreg = dv * dinv[s];
        }
        int j = 0;
        for (; j + 4 <= cnt; j += 4) {
            int s0 = __shfl(sreg, j),     s1 = __shfl(sreg, j + 1);
            int s2 = __shfl(sreg, j + 2), s3 = __shfl(sreg, j + 3);
            float w0 = __shfl(wreg, j),     w1 = __shfl(wreg, j + 1);
            float w2 = __shfl(wreg, j + 2), w3 = __shfl(wreg, j + 3);
            uint4 p0 = *(const uint4*)(h + (size_t)s0 * C_HID + lane * 8);
            uint4 p1 = *(const uint4*)(h + (size_t)s1 * C_HID + lane * 8);
            uint4 p2 = *(const uint4*)(h + (size_t)s2 * C_HID + lane * 8);
            uint4 p3 = *(const uint4*)(h + (size_t)s3 * C_HID + lane * 8);
            accum8(acc, p0, w0); accum8(acc, p1, w1);
            accum8(acc, p2, w2); accum8(acc, p3, w3);
        }
        for (; j < cnt; ++j) {
            int sj = __shfl(sreg, j);
            float wj = __shfl(wreg, j);
            uint4 pj = *(const uint4*)(h + (size_t)sj * C_HID + lane * 8);
            accum8(acc, pj, wj);
        }
    }

    float4 ba = *(const float4*)(b1f + lane * 8);
    float4 bb = *(const float4*)(b1f + lane * 8 + 4);
    float r0 = fmaxf(acc[0] + ba.x, 0.f), r1 = fmaxf(acc[1] + ba.y, 0.f);
    float r2 = fmaxf(acc[2] + ba.z, 0.f), r3 = fmaxf(acc[3] + ba.w, 0.f);
    float r4 = fmaxf(acc[4] + bb.x, 0.f), r5 = fmaxf(acc[5] + bb.y, 0.f);
    float r6 = fmaxf(acc[6] + bb.z, 0.f), r7 = fmaxf(acc[7] + bb.w, 0.f);
    uint4 o;
    o.x = (u32)f2bf(r0) | ((u32)f2bf(r1) << 16);
    o.y = (u32)f2bf(r2) | ((u32)f2bf(r3) << 16);
    o.z = (u32)f2bf(r4) | ((u32)f2bf(r5) << 16);
    o.w = (u32)f2bf(r6) | ((u32)f2bf(r7) << 16);
    *(uint4*)(out + (size_t)v * C_HID + lane * 8) = o;
}

// ---------------- agg2 + bias + log_softmax (same MLP pattern) ----------------
__global__ __launch_bounds__(256) void k_agg2(
    const float* __restrict__ h2, const int* __restrict__ csr, const int* __restrict__ offs,
    const float* __restrict__ dinv, const float* __restrict__ b2f,
    const int* __restrict__ flags, void* __restrict__ out, int n, int Etot) {
    int wave = threadIdx.x >> 6, lane = threadIdx.x & 63;
    int v = blockIdx.x * 4 + wave;
    if (v >= n) return;
    float dv = dinv[v];
    float acc = 0.f;
    if (lane < C_OUT) acc = dv * dv * h2[(size_t)v * C_OUT + lane];

    int e0 = imax(0, imin(offs[v], Etot));
    int e1 = imax(e0, imin(offs[v + 1], Etot));
    int lidx = (lane < C_OUT) ? lane : 0;
    for (int base = e0; base < e1; base += 64) {
        int cnt = imin(64, e1 - base);
        int sreg = 0; float wreg = 0.f;
        if (lane < cnt) {
            u32 s = (u32)csr[base + lane];
            s = (s < (u32)n) ? s : 0u;
            sreg = (int)s;
            wreg = dv * dinv[s];
        }
        int j = 0;
        for (; j + 4 <= cnt; j += 4) {
            int s0 = __shfl(sreg, j),     s1 = __shfl(sreg, j + 1);
            int s2 = __shfl(sreg, j + 2), s3 = __shfl(sreg, j + 3);
            float w0 = __shfl(wreg, j),     w1 = __shfl(wreg, j + 1);
            float w2 = __shfl(wreg, j + 2), w3 = __shfl(wreg, j + 3);
            float p0 = h2[(size_t)s0 * C_OUT + lidx];
            float p1 = h2[(size_t)s1 * C_OUT + lidx];
            float p2 = h2[(size_t)s2 * C_OUT + lidx];
            float p3 = h2[(size_t)s3 * C_OUT + lidx];
            if (lane < C_OUT) acc += w0 * p0 + w1 * p1 + w2 * p2 + w3 * p3;
        }
        for (; j < cnt; ++j) {
            int sj = __shfl(sreg, j);
            float wj = __shfl(wreg, j);
            float pj = h2[(size_t)sj * C_OUT + lidx];
            if (lane < C_OUT) acc += wj * pj;
        }
    }

    if (lane < C_OUT) acc += b2f[lane];
    float m = (lane < C_OUT) ? acc : -1e30f;
    for (int off = 32; off > 0; off >>= 1) m = fmaxf(m, __shfl_xor(m, off));
    float ex = (lane < C_OUT) ? expf(acc - m) : 0.f;
    float sum = ex;
    for (int off = 32; off > 0; off >>= 1) sum += __shfl_xor(sum, off);
    if (lane < C_OUT) {
        float r = acc - m - logf(sum);
        if (flags[1]) ((u16*)out)[(size_t)v * C_OUT + lane] = f2bf(r);
        else ((float*)out)[(size_t)v * C_OUT + lane] = r;
    }
}

// ---------------- launch ----------------

extern "C" void kernel_launch(void* const* d_in, const int* in_sizes, int n_in,
                              void* d_out, int out_size, void* d_ws, size_t ws_size,
                              hipStream_t stream) {
    const void* x = d_in[0];
    const int* ei = (const int*)d_in[1];
    const void* W1 = d_in[2];
    const void* b1 = d_in[3];
    const void* W2 = d_in[4];
    const void* b2 = d_in[5];

    const int N = out_size / C_OUT;
    const int Mx = in_sizes[0] / C_IN;
    const int M = (N < Mx) ? N : Mx;
    const int ECAP = in_sizes[1];
    const int E = ECAP / 2;

    char* p = (char*)d_ws;
    size_t used = 0;
    auto carve = [&](size_t bytes) -> void* {
        void* r = (void*)p;
        size_t b = (bytes + 255) & ~(size_t)255;
        p += b; used += b;
        return r;
    };
    int* flags = (int*)carve(256);
    int* deg = (int*)carve((size_t)N * 4);
    int* cursor = (int*)carve((size_t)N * 4);
    float* dinv = (float*)carve((size_t)N * 4);
    int* offs = (int*)carve((size_t)(N + 1) * 4);
    int* bsum = (int*)carve(8192);
    int* csr = (int*)carve((size_t)E * 4);
    u16* w1t = (u16*)carve((size_t)C_HID * C_IN * 2);
    u16* w2t = (u16*)carve((size_t)64 * C_HID * 2);
    float* b1f = (float*)carve(C_HID * 4);
    float* b2f = (float*)carve(256);
    u16* bufA = (u16*)carve((size_t)N * C_HID * 2);
    u16* bufB = (u16*)carve((size_t)N * C_HID * 2);
    if (used > ws_size) return;

    u16* xbf = bufA;
    u16* hbf = bufB;
    u16* hagg = bufA;
    float* h2 = (float*)bufB;

    const int NB = (N + 255) / 256;
    const int EB = (E + 255) / 256;

    k_detect<<<1, 64, 0, stream>>>((const u32*)x, ei, flags);

    k_init<<<NB, 256, 0, stream>>>(deg, cursor, N);
    k_deg<<<EB, 256, 0, stream>>>(ei, flags, deg, E, ECAP, N);
    k_dinv<<<NB, 256, 0, stream>>>(deg, dinv, N);
    k_scanA<<<NB, 256, 0, stream>>>(deg, bsum, N);
    k_scanB<<<1, 64, 0, stream>>>(bsum, NB, offs, N);
    k_scanC<<<NB, 256, 0, stream>>>(deg, bsum, offs, N);
    k_sort<<<EB, 256, 0, stream>>>(ei, flags, offs, cursor, csr, E, ECAP, N);

    k_convx<<<(M * C_IN + 255) / 256, 256, 0, stream>>>(x, flags, xbf, M * C_IN);
    k_w1t<<<(C_IN * C_HID) / 256, 256, 0, stream>>>(W1, flags, w1t);
    k_w2t<<<(64 * C_HID) / 256, 256, 0, stream>>>(W2, flags, w2t);
    k_bias<<<2, 256, 0, stream>>>(b1, b2, flags, b1f, b2f);

    dim3 g1((N + 63) / 64, C_HID / 64);
    k_gemm_bt<true><<<g1, 256, 0, stream>>>(xbf, w1t, (void*)hbf, M, C_IN, C_HID, C_HID);

    k_agg1<<<(N + 3) / 4, 256, 0, stream>>>(hbf, csr, offs, dinv, b1f, hagg, N, E);

    dim3 g2((N + 63) / 64, 1);
    k_gemm_bt<false><<<g2, 256, 0, stream>>>(hagg, w2t, (void*)h2, N, C_HID, C_OUT, C_OUT);

    k_agg2<<<(N + 3) / 4, 256, 0, stream>>>(h2, csr, offs, dinv, b2f, flags, d_out, N, E);
}

// Round 6
// 536.191 us; speedup vs baseline: 1.2507x; 1.0407x over previous
//
#include <hip/hip_runtime.h>

// GCN 2-layer forward on gfx950.
// R6: agg unroll-8 (deeper MLP), 128x128 GEMM1 tile (m93 structure),
//     bf16 x consumed directly (convx early-out).

typedef unsigned int u32;
typedef unsigned short u16;
typedef __bf16 bf16x8 __attribute__((ext_vector_type(8)));
typedef float f32x4 __attribute__((ext_vector_type(4)));

#define C_IN 512
#define C_HID 512
#define C_OUT 40

__device__ __forceinline__ float bf2f(u16 u) {
    u32 x = ((u32)u) << 16;
    return __builtin_bit_cast(float, x);
}
__device__ __forceinline__ u16 f2bf(float f) {
    u32 x = __builtin_bit_cast(u32, f);
    x += 0x7fffu + ((x >> 16) & 1u);   // RNE
    return (u16)(x >> 16);
}
__host__ __device__ __forceinline__ int imin(int a, int b) { return a < b ? a : b; }
__host__ __device__ __forceinline__ int imax(int a, int b) { return a > b ? a : b; }

// ---------------- dtype detection ----------------
__global__ void k_detect(const u32* __restrict__ x32, const int* __restrict__ ei,
                         int* flags) {
    if (blockIdx.x || threadIdx.x) return;
    int zeros = 0;
    for (int k = 0; k < 128; ++k) zeros += (ei[2 * k + 1] == 0);
    int votes = 0;
    for (int i = 0; i < 128; ++i) {
        u32 e = (x32[i] >> 7) & 0xff;
        votes += (e >= 110 && e <= 133);
    }
    flags[0] = (zeros == 128) ? 2 : 1;   // int32 step per edge element
    flags[1] = (votes >= 96) ? 1 : 0;    // floats bf16-packed?
}

// ---------------- graph preprocessing ----------------

__global__ void k_init(int* deg, int* cursor, int n) {
    int i = blockIdx.x * 256 + threadIdx.x;
    if (i < n) { deg[i] = 1; cursor[i] = 0; }
}

__global__ void k_deg(const int* __restrict__ ei, const int* __restrict__ flags,
                      int* deg, int E, int ecap, int n) {
    int e = blockIdx.x * 256 + threadIdx.x;
    if (e >= E) return;
    int st = flags[0];
    int cap = ecap * st - 1;
    u32 d = (u32)ei[imin((E + e) * st, cap)];
    if (d < (u32)n) atomicAdd(&deg[d], 1);
}

__global__ void k_dinv(const int* __restrict__ deg, float* dinv, int n) {
    int i = blockIdx.x * 256 + threadIdx.x;
    if (i < n) dinv[i] = rsqrtf((float)imax(deg[i], 1));
}

__global__ void k_scanA(const int* __restrict__ deg, int* bsum, int n) {
    __shared__ int sh[256];
    int i = blockIdx.x * 256 + threadIdx.x;
    sh[threadIdx.x] = (i < n) ? deg[i] - 1 : 0;
    __syncthreads();
    for (int d = 128; d > 0; d >>= 1) {
        if (threadIdx.x < d) sh[threadIdx.x] += sh[threadIdx.x + d];
        __syncthreads();
    }
    if (threadIdx.x == 0) bsum[blockIdx.x] = sh[0];
}

__global__ void k_scanB(int* bsum, int nb, int* offs, int n) {
    if (threadIdx.x == 0 && blockIdx.x == 0) {
        int run = 0;
        for (int b = 0; b < nb; ++b) { int t = bsum[b]; bsum[b] = run; run += t; }
        offs[n] = run;
    }
}

__global__ void k_scanC(const int* __restrict__ deg, const int* __restrict__ bsum,
                        int* offs, int n) {
    __shared__ int sh[256];
    int t = threadIdx.x;
    int i = blockIdx.x * 256 + t;
    int v = (i < n) ? deg[i] - 1 : 0;
    sh[t] = v;
    __syncthreads();
    for (int d = 1; d < 256; d <<= 1) {
        int add = (t >= d) ? sh[t - d] : 0;
        __syncthreads();
        sh[t] += add;
        __syncthreads();
    }
    if (i < n) offs[i] = bsum[blockIdx.x] + sh[t] - v;
}

__global__ void k_sort(const int* __restrict__ ei, const int* __restrict__ flags,
                       const int* __restrict__ offs, int* cursor, int* csr,
                       int E, int ecap, int n) {
    int e = blockIdx.x * 256 + threadIdx.x;
    if (e >= E) return;
    int st = flags[0];
    int cap = ecap * st - 1;
    u32 d = (u32)ei[imin((E + e) * st, cap)];
    u32 s = (u32)ei[imin(e * st, cap)];
    if (d < (u32)n && s < (u32)n) {
        int pos = offs[d] + atomicAdd(&cursor[(int)d], 1);
        if ((u32)pos < (u32)E) csr[pos] = (int)s;
    }
}

// ---------------- conversions ----------------

__device__ __forceinline__ float ldf(const void* p, int i, int isbf) {
    return isbf ? bf2f(((const u16*)p)[i]) : ((const float*)p)[i];
}

// only needed when x is fp32; bf16 x is consumed directly by GEMM1
__global__ void k_convx(const void* __restrict__ x, const int* __restrict__ flags,
                        u16* __restrict__ out, int nelem) {
    if (flags[1]) return;
    int i = blockIdx.x * 256 + threadIdx.x;
    if (i >= nelem) return;
    out[i] = f2bf(((const float*)x)[i]);
}

__global__ void k_w1t(const void* __restrict__ W, const int* __restrict__ flags,
                      u16* __restrict__ out) {
    int id = blockIdx.x * 256 + threadIdx.x;
    int n = id >> 9, k = id & 511;
    out[n * 512 + k] = f2bf(ldf(W, k * 512 + n, flags[1]));
}

__global__ void k_w2t(const void* __restrict__ W, const int* __restrict__ flags,
                      u16* __restrict__ out) {
    int id = blockIdx.x * 256 + threadIdx.x;
    int n = id >> 9, k = id & 511;
    out[id] = (n < C_OUT) ? f2bf(ldf(W, k * C_OUT + n, flags[1])) : (u16)0;
}

__global__ void k_bias(const void* __restrict__ b1, const void* __restrict__ b2,
                       const int* __restrict__ flags, float* __restrict__ b1f,
                       float* __restrict__ b2f) {
    int i = threadIdx.x + blockIdx.x * 256;
    int isbf = flags[1];
    if (i < C_HID) b1f[i] = ldf(b1, i, isbf);
    if (i < C_OUT) b2f[i] = ldf(b2, i, isbf);
}

// ---------------- GEMM1: 128x128 tile, bf16 out ----------------
// 4 waves in 2x2; each wave computes 4x4 MFMA 16x16 tiles (64x64).
// verified layouts (learn_hip m89/m91/m120):
//   A frag: A[m=lane&15][k=(lane>>4)*8+j]; B frag == Bt[n=lane&15][k]
//   C/D: row=(lane>>4)*4+reg, col=lane&15
__global__ __launch_bounds__(256) void k_gemm128(
    const u16* __restrict__ xdir, const u16* __restrict__ xcvt,
    const int* __restrict__ flags, const u16* __restrict__ Bt,
    u16* __restrict__ C, int M, int K, int ldc) {
    const u16* A = flags[1] ? xdir : xcvt;
    __shared__ __align__(16) u16 As[128 * 32];
    __shared__ __align__(16) u16 Bs[128 * 32];
    int tid = threadIdx.x;
    int wave = tid >> 6, lane = tid & 63;
    int quad = lane >> 4, lrow = lane & 15;
    int wrow = (wave & 1) * 64, wcol = (wave >> 1) * 64;
    int row0 = blockIdx.x * 128;
    int n0 = blockIdx.y * 128;
    int srow = tid >> 1;            // 0..127
    int scol = (tid & 1) * 16;      // 0 or 16

    f32x4 acc[4][4] = {};
    int kTiles = K >> 5;
    for (int kt = 0; kt < kTiles; ++kt) {
        int k0 = kt * 32;
        uint4 a0 = make_uint4(0, 0, 0, 0), a1 = make_uint4(0, 0, 0, 0);
        int gr = row0 + srow;
        if (gr < M) {
            const u16* ap = A + (size_t)gr * K + k0 + scol;
            a0 = *(const uint4*)ap;
            a1 = *(const uint4*)(ap + 8);
        }
        const u16* bp = Bt + (size_t)(n0 + srow) * K + k0 + scol;
        uint4 b0 = *(const uint4*)bp;
        uint4 b1 = *(const uint4*)(bp + 8);
        __syncthreads();
        *(uint4*)(As + srow * 32 + scol) = a0;
        *(uint4*)(As + srow * 32 + scol + 8) = a1;
        *(uint4*)(Bs + srow * 32 + scol) = b0;
        *(uint4*)(Bs + srow * 32 + scol + 8) = b1;
        __syncthreads();
        bf16x8 af[4], bfr[4];
#pragma unroll
        for (int i = 0; i < 4; ++i)
            af[i] = *(const bf16x8*)(As + (wrow + i * 16 + lrow) * 32 + quad * 8);
#pragma unroll
        for (int j = 0; j < 4; ++j)
            bfr[j] = *(const bf16x8*)(Bs + (wcol + j * 16 + lrow) * 32 + quad * 8);
#pragma unroll
        for (int i = 0; i < 4; ++i)
#pragma unroll
            for (int j = 0; j < 4; ++j)
                acc[i][j] = __builtin_amdgcn_mfma_f32_16x16x32_bf16(af[i], bfr[j],
                                                                    acc[i][j], 0, 0, 0);
    }
#pragma unroll
    for (int i = 0; i < 4; ++i)
#pragma unroll
        for (int j = 0; j < 4; ++j)
#pragma unroll
            for (int r = 0; r < 4; ++r) {
                int row = row0 + wrow + i * 16 + quad * 4 + r;
                int col = n0 + wcol + j * 16 + lrow;
                if (row < M) C[(size_t)row * ldc + col] = f2bf(acc[i][j][r]);
            }
}

// ---------------- GEMM2: 64x64 tile, fp32 out (small) ----------------
__global__ __launch_bounds__(256) void k_gemm64(
    const u16* __restrict__ A, const u16* __restrict__ Bt, float* __restrict__ Cout,
    int M, int K, int Ncols, int ldc) {
    __shared__ __align__(16) u16 As[64 * 32];
    __shared__ __align__(16) u16 Bs[64 * 32];
    int tid = threadIdx.x;
    int wave = tid >> 6, lane = tid & 63;
    int quad = lane >> 4, lrow = lane & 15;
    int row0 = blockIdx.x * 64;
    int n0 = blockIdx.y * 64;
    int srow = tid >> 2;
    int skc = (tid & 3) * 8;

    f32x4 acc[4] = {};
    int kTiles = K >> 5;
    for (int kt = 0; kt < kTiles; ++kt) {
        int k0 = kt * 32;
        uint4 av = make_uint4(0, 0, 0, 0);
        int gr = row0 + srow;
        if (gr < M) av = *(const uint4*)(A + (size_t)gr * K + k0 + skc);
        uint4 bv = *(const uint4*)(Bt + (size_t)(n0 + srow) * K + k0 + skc);
        __syncthreads();
        *(uint4*)(As + srow * 32 + skc) = av;
        *(uint4*)(Bs + srow * 32 + skc) = bv;
        __syncthreads();
        bf16x8 af = *(const bf16x8*)(As + (wave * 16 + lrow) * 32 + quad * 8);
#pragma unroll
        for (int t = 0; t < 4; ++t) {
            bf16x8 bfr = *(const bf16x8*)(Bs + (t * 16 + lrow) * 32 + quad * 8);
            acc[t] = __builtin_amdgcn_mfma_f32_16x16x32_bf16(af, bfr, acc[t], 0, 0, 0);
        }
    }
#pragma unroll
    for (int t = 0; t < 4; ++t)
#pragma unroll
        for (int r = 0; r < 4; ++r) {
            int row = wave * 16 + quad * 4 + r;
            int col = t * 16 + lrow;
            int gr = row0 + row, gc = n0 + col;
            if (gr < M && gc < Ncols) Cout[(size_t)gr * ldc + gc] = acc[t][r];
        }
}

// ---------------- agg1: hagg = ReLU(Anorm*h + b1), bf16 in/out ----------------
// wave-per-node; 64 lanes x 8 features; shfl-broadcast indices; unroll-8 MLP.

__device__ __forceinline__ void accum8(float* acc, uint4 p, float w) {
    acc[0] += w * bf2f((u16)p.x); acc[1] += w * bf2f((u16)(p.x >> 16));
    acc[2] += w * bf2f((u16)p.y); acc[3] += w * bf2f((u16)(p.y >> 16));
    acc[4] += w * bf2f((u16)p.z); acc[5] += w * bf2f((u16)(p.z >> 16));
    acc[6] += w * bf2f((u16)p.w); acc[7] += w * bf2f((u16)(p.w >> 16));
}

__global__ __launch_bounds__(256) void k_agg1(
    const u16* __restrict__ h, const int* __restrict__ csr, const int* __restrict__ offs,
    const float* __restrict__ dinv, const float* __restrict__ b1f,
    u16* __restrict__ out, int n, int Etot) {
    int wave = threadIdx.x >> 6, lane = threadIdx.x & 63;
    int v = blockIdx.x * 4 + wave;
    if (v >= n) return;   // wave-uniform
    float dv = dinv[v];
    float wself = dv * dv;

    float acc[8];
    uint4 hs = *(const uint4*)(h + (size_t)v * C_HID + lane * 8);
    acc[0] = wself * bf2f((u16)hs.x); acc[1] = wself * bf2f((u16)(hs.x >> 16));
    acc[2] = wself * bf2f((u16)hs.y); acc[3] = wself * bf2f((u16)(hs.y >> 16));
    acc[4] = wself * bf2f((u16)hs.z); acc[5] = wself * bf2f((u16)(hs.z >> 16));
    acc[6] = wself * bf2f((u16)hs.w); acc[7] = wself * bf2f((u16)(hs.w >> 16));

    int e0 = imax(0, imin(offs[v], Etot));
    int e1 = imax(e0, imin(offs[v + 1], Etot));
    for (int base = e0; base < e1; base += 64) {
        int cnt = imin(64, e1 - base);
        int sreg = 0; float wreg = 0.f;
        if (lane < cnt) {
            u32 s = (u32)csr[base + lane];
            s = (s < (u32)n) ? s : 0u;
            sreg = (int)s;
            wreg = dv * dinv[s];
        }
        int j = 0;
        for (; j + 8 <= cnt; j += 8) {
            int ss[8]; float ww[8]; uint4 pp[8];
#pragma unroll
            for (int t = 0; t < 8; ++t) {
                ss[t] = __shfl(sreg, j + t);
                ww[t] = __shfl(wreg, j + t);
            }
#pragma unroll
            for (int t = 0; t < 8; ++t)
                pp[t] = *(const uint4*)(h + (size_t)ss[t] * C_HID + lane * 8);
#pragma unroll
            for (int t = 0; t < 8; ++t) accum8(acc, pp[t], ww[t]);
        }
        for (; j + 2 <= cnt; j += 2) {
            int s0 = __shfl(sreg, j), s1 = __shfl(sreg, j + 1);
            float w0 = __shfl(wreg, j), w1 = __shfl(wreg, j + 1);
            uint4 p0 = *(const uint4*)(h + (size_t)s0 * C_HID + lane * 8);
            uint4 p1 = *(const uint4*)(h + (size_t)s1 * C_HID + lane * 8);
            accum8(acc, p0, w0); accum8(acc, p1, w1);
        }
        for (; j < cnt; ++j) {
            int sj = __shfl(sreg, j);
            float wj = __shfl(wreg, j);
            uint4 pj = *(const uint4*)(h + (size_t)sj * C_HID + lane * 8);
            accum8(acc, pj, wj);
        }
    }

    float4 ba = *(const float4*)(b1f + lane * 8);
    float4 bb = *(const float4*)(b1f + lane * 8 + 4);
    float r0 = fmaxf(acc[0] + ba.x, 0.f), r1 = fmaxf(acc[1] + ba.y, 0.f);
    float r2 = fmaxf(acc[2] + ba.z, 0.f), r3 = fmaxf(acc[3] + ba.w, 0.f);
    float r4 = fmaxf(acc[4] + bb.x, 0.f), r5 = fmaxf(acc[5] + bb.y, 0.f);
    float r6 = fmaxf(acc[6] + bb.z, 0.f), r7 = fmaxf(acc[7] + bb.w, 0.f);
    uint4 o;
    o.x = (u32)f2bf(r0) | ((u32)f2bf(r1) << 16);
    o.y = (u32)f2bf(r2) | ((u32)f2bf(r3) << 16);
    o.z = (u32)f2bf(r4) | ((u32)f2bf(r5) << 16);
    o.w = (u32)f2bf(r6) | ((u32)f2bf(r7) << 16);
    *(uint4*)(out + (size_t)v * C_HID + lane * 8) = o;
}

// ---------------- agg2 + bias + log_softmax ----------------
__global__ __launch_bounds__(256) void k_agg2(
    const float* __restrict__ h2, const int* __restrict__ csr, const int* __restrict__ offs,
    const float* __restrict__ dinv, const float* __restrict__ b2f,
    const int* __restrict__ flags, void* __restrict__ out, int n, int Etot) {
    int wave = threadIdx.x >> 6, lane = threadIdx.x & 63;
    int v = blockIdx.x * 4 + wave;
    if (v >= n) return;
    float dv = dinv[v];
    float acc = 0.f;
    if (lane < C_OUT) acc = dv * dv * h2[(size_t)v * C_OUT + lane];

    int e0 = imax(0, imin(offs[v], Etot));
    int e1 = imax(e0, imin(offs[v + 1], Etot));
    int lidx = (lane < C_OUT) ? lane : 0;
    for (int base = e0; base < e1; base += 64) {
        int cnt = imin(64, e1 - base);
        int sreg = 0; float wreg = 0.f;
        if (lane < cnt) {
            u32 s = (u32)csr[base + lane];
            s = (s < (u32)n) ? s : 0u;
            sreg = (int)s;
            wreg = dv * dinv[s];
        }
        int j = 0;
        for (; j + 8 <= cnt; j += 8) {
            int ss[8]; float ww[8]; float pv[8];
#pragma unroll
            for (int t = 0; t < 8; ++t) {
                ss[t] = __shfl(sreg, j + t);
                ww[t] = __shfl(wreg, j + t);
            }
#pragma unroll
            for (int t = 0; t < 8; ++t) pv[t] = h2[(size_t)ss[t] * C_OUT + lidx];
            if (lane < C_OUT) {
#pragma unroll
                for (int t = 0; t < 8; ++t) acc += ww[t] * pv[t];
            }
        }
        for (; j < cnt; ++j) {
            int sj = __shfl(sreg, j);
            float wj = __shfl(wreg, j);
            float pj = h2[(size_t)sj * C_OUT + lidx];
            if (lane < C_OUT) acc += wj * pj;
        }
    }

    if (lane < C_OUT) acc += b2f[lane];
    float m = (lane < C_OUT) ? acc : -1e30f;
    for (int off = 32; off > 0; off >>= 1) m = fmaxf(m, __shfl_xor(m, off));
    float ex = (lane < C_OUT) ? expf(acc - m) : 0.f;
    float sum = ex;
    for (int off = 32; off > 0; off >>= 1) sum += __shfl_xor(sum, off);
    if (lane < C_OUT) {
        float r = acc - m - logf(sum);
        if (flags[1]) ((u16*)out)[(size_t)v * C_OUT + lane] = f2bf(r);
        else ((float*)out)[(size_t)v * C_OUT + lane] = r;
    }
}

// ---------------- launch ----------------

extern "C" void kernel_launch(void* const* d_in, const int* in_sizes, int n_in,
                              void* d_out, int out_size, void* d_ws, size_t ws_size,
                              hipStream_t stream) {
    const void* x = d_in[0];
    const int* ei = (const int*)d_in[1];
    const void* W1 = d_in[2];
    const void* b1 = d_in[3];
    const void* W2 = d_in[4];
    const void* b2 = d_in[5];

    const int N = out_size / C_OUT;
    const int Mx = in_sizes[0] / C_IN;
    const int M = (N < Mx) ? N : Mx;
    const int ECAP = in_sizes[1];
    const int E = ECAP / 2;

    char* p = (char*)d_ws;
    size_t used = 0;
    auto carve = [&](size_t bytes) -> void* {
        void* r = (void*)p;
        size_t b = (bytes + 255) & ~(size_t)255;
        p += b; used += b;
        return r;
    };
    int* flags = (int*)carve(256);
    int* deg = (int*)carve((size_t)N * 4);
    int* cursor = (int*)carve((size_t)N * 4);
    float* dinv = (float*)carve((size_t)N * 4);
    int* offs = (int*)carve((size_t)(N + 1) * 4);
    int* bsum = (int*)carve(8192);
    int* csr = (int*)carve((size_t)E * 4);
    u16* w1t = (u16*)carve((size_t)C_HID * C_IN * 2);
    u16* w2t = (u16*)carve((size_t)64 * C_HID * 2);
    float* b1f = (float*)carve(C_HID * 4);
    float* b2f = (float*)carve(256);
    u16* bufA = (u16*)carve((size_t)N * C_HID * 2);   // xcvt (fp32 case), then hagg
    u16* bufB = (u16*)carve((size_t)N * C_HID * 2);   // hbf, then h2 (fp32)
    if (used > ws_size) return;

    u16* xcvt = bufA;
    u16* hbf = bufB;
    u16* hagg = bufA;
    float* h2 = (float*)bufB;

    const int NB = (N + 255) / 256;
    const int EB = (E + 255) / 256;

    k_detect<<<1, 64, 0, stream>>>((const u32*)x, ei, flags);

    k_init<<<NB, 256, 0, stream>>>(deg, cursor, N);
    k_deg<<<EB, 256, 0, stream>>>(ei, flags, deg, E, ECAP, N);
    k_dinv<<<NB, 256, 0, stream>>>(deg, dinv, N);
    k_scanA<<<NB, 256, 0, stream>>>(deg, bsum, N);
    k_scanB<<<1, 64, 0, stream>>>(bsum, NB, offs, N);
    k_scanC<<<NB, 256, 0, stream>>>(deg, bsum, offs, N);
    k_sort<<<EB, 256, 0, stream>>>(ei, flags, offs, cursor, csr, E, ECAP, N);

    k_convx<<<(M * C_IN + 255) / 256, 256, 0, stream>>>(x, flags, xcvt, M * C_IN);
    k_w1t<<<(C_IN * C_HID) / 256, 256, 0, stream>>>(W1, flags, w1t);
    k_w2t<<<(64 * C_HID) / 256, 256, 0, stream>>>(W2, flags, w2t);
    k_bias<<<2, 256, 0, stream>>>(b1, b2, flags, b1f, b2f);

    dim3 g1((M + 127) / 128, C_HID / 128);
    k_gemm128<<<g1, 256, 0, stream>>>((const u16*)x, xcvt, flags, w1t, hbf,
                                      M, C_IN, C_HID);

    k_agg1<<<(N + 3) / 4, 256, 0, stream>>>(hbf, csr, offs, dinv, b1f, hagg, N, E);

    dim3 g2((N + 63) / 64, 1);
    k_gemm64<<<g2, 256, 0, stream>>>(hagg, w2t, h2, N, C_HID, C_OUT, C_OUT);

    k_agg2<<<(N + 3) / 4, 256, 0, stream>>>(h2, csr, offs, dinv, b2f, flags, d_out, N, E);
}

// Round 7
// 532.074 us; speedup vs baseline: 1.2603x; 1.0077x over previous
//
#include <hip/hip_runtime.h>

// GCN 2-layer forward on gfx950.
// R7: bucketed CSR — edges counting-sorted by (dst, src>>11) so concurrently
//     executing waves gather h[src] from a ~2MB L2-resident window.
//     agg kernels unchanged (order-agnostic); deg derived from bucket rows.

typedef unsigned int u32;
typedef unsigned short u16;
typedef __bf16 bf16x8 __attribute__((ext_vector_type(8)));
typedef float f32x4 __attribute__((ext_vector_type(4)));

#define C_IN 512
#define C_HID 512
#define C_OUT 40
#define BSHIFT 11   // src-bucket = src >> 11  (2048 rows = 2 MB of h)

__device__ __forceinline__ float bf2f(u16 u) {
    u32 x = ((u32)u) << 16;
    return __builtin_bit_cast(float, x);
}
__device__ __forceinline__ u16 f2bf(float f) {
    u32 x = __builtin_bit_cast(u32, f);
    x += 0x7fffu + ((x >> 16) & 1u);   // RNE
    return (u16)(x >> 16);
}
__host__ __device__ __forceinline__ int imin(int a, int b) { return a < b ? a : b; }
__host__ __device__ __forceinline__ int imax(int a, int b) { return a > b ? a : b; }

// ---------------- dtype detection ----------------
__global__ void k_detect(const u32* __restrict__ x32, const int* __restrict__ ei,
                         int* flags) {
    if (blockIdx.x || threadIdx.x) return;
    int zeros = 0;
    for (int k = 0; k < 128; ++k) zeros += (ei[2 * k + 1] == 0);
    int votes = 0;
    for (int i = 0; i < 128; ++i) {
        u32 e = (x32[i] >> 7) & 0xff;
        votes += (e >= 110 && e <= 133);
    }
    flags[0] = (zeros == 128) ? 2 : 1;   // int32 step per edge element
    flags[1] = (votes >= 96) ? 1 : 0;    // floats bf16-packed?
}

// ---------------- bucketed-CSR build ----------------

__global__ void k_zero(int* a, int n) {
    int i = blockIdx.x * 256 + threadIdx.x;
    if (i < n) a[i] = 0;
}

__global__ void k_count(const int* __restrict__ ei, const int* __restrict__ flags,
                        int* count, int E, int ecap, int n, int nbk) {
    int e = blockIdx.x * 256 + threadIdx.x;
    if (e >= E) return;
    int st = flags[0];
    int cap = ecap * st - 1;
    u32 d = (u32)ei[imin((E + e) * st, cap)];
    u32 s = (u32)ei[imin(e * st, cap)];
    if (d < (u32)n && s < (u32)n)
        atomicAdd(&count[(int)d * nbk + (int)(s >> BSHIFT)], 1);
}

// per-256-block sums
__global__ void k_blksum(const int* __restrict__ a, int* bs, int n) {
    __shared__ int sh[256];
    int i = blockIdx.x * 256 + threadIdx.x;
    sh[threadIdx.x] = (i < n) ? a[i] : 0;
    __syncthreads();
    for (int d = 128; d > 0; d >>= 1) {
        if (threadIdx.x < d) sh[threadIdx.x] += sh[threadIdx.x + d];
        __syncthreads();
    }
    if (threadIdx.x == 0) bs[blockIdx.x] = sh[0];
}

__global__ void k_scansmall(int* bs, int nb, int* total) {
    if (blockIdx.x || threadIdx.x) return;
    int run = 0;
    for (int b = 0; b < nb; ++b) { int t = bs[b]; bs[b] = run; run += t; }
    *total = run;
}

// out[i] = base[blk] + exclusive-prefix within block of in[i]  (in==out ok)
__global__ void k_scanadd(const int* __restrict__ in, const int* __restrict__ base,
                          int* out, int n) {
    __shared__ int sh[256];
    int t = threadIdx.x;
    int i = blockIdx.x * 256 + t;
    int v = (i < n) ? in[i] : 0;
    sh[t] = v;
    __syncthreads();
    for (int d = 1; d < 256; d <<= 1) {
        int add = (t >= d) ? sh[t - d] : 0;
        __syncthreads();
        sh[t] += add;
        __syncthreads();
    }
    if (i < n) out[i] = base[blockIdx.x] + sh[t] - v;
}

__global__ void k_place(const int* __restrict__ ei, const int* __restrict__ flags,
                        const int* __restrict__ offs, int* cursor, int* csr,
                        int E, int ecap, int n, int nbk) {
    int e = blockIdx.x * 256 + threadIdx.x;
    if (e >= E) return;
    int st = flags[0];
    int cap = ecap * st - 1;
    u32 d = (u32)ei[imin((E + e) * st, cap)];
    u32 s = (u32)ei[imin(e * st, cap)];
    if (d < (u32)n && s < (u32)n) {
        int key = (int)d * nbk + (int)(s >> BSHIFT);
        int pos = offs[key] + atomicAdd(&cursor[key], 1);
        if ((u32)pos < (u32)E) csr[pos] = (int)s;
    }
}

__global__ void k_dinv(const int* __restrict__ offs, float* dinv, int n, int nbk) {
    int i = blockIdx.x * 256 + threadIdx.x;
    if (i < n) {
        int deg = 1 + offs[(i + 1) * nbk] - offs[i * nbk];
        dinv[i] = rsqrtf((float)imax(deg, 1));
    }
}

// ---------------- conversions ----------------

__device__ __forceinline__ float ldf(const void* p, int i, int isbf) {
    return isbf ? bf2f(((const u16*)p)[i]) : ((const float*)p)[i];
}

__global__ void k_convx(const void* __restrict__ x, const int* __restrict__ flags,
                        u16* __restrict__ out, int nelem) {
    if (flags[1]) return;   // bf16 x consumed directly
    int i = blockIdx.x * 256 + threadIdx.x;
    if (i >= nelem) return;
    out[i] = f2bf(((const float*)x)[i]);
}

__global__ void k_w1t(const void* __restrict__ W, const int* __restrict__ flags,
                      u16* __restrict__ out) {
    int id = blockIdx.x * 256 + threadIdx.x;
    int n = id >> 9, k = id & 511;
    out[n * 512 + k] = f2bf(ldf(W, k * 512 + n, flags[1]));
}

__global__ void k_w2t(const void* __restrict__ W, const int* __restrict__ flags,
                      u16* __restrict__ out) {
    int id = blockIdx.x * 256 + threadIdx.x;
    int n = id >> 9, k = id & 511;
    out[id] = (n < C_OUT) ? f2bf(ldf(W, k * C_OUT + n, flags[1])) : (u16)0;
}

__global__ void k_bias(const void* __restrict__ b1, const void* __restrict__ b2,
                       const int* __restrict__ flags, float* __restrict__ b1f,
                       float* __restrict__ b2f) {
    int i = threadIdx.x + blockIdx.x * 256;
    int isbf = flags[1];
    if (i < C_HID) b1f[i] = ldf(b1, i, isbf);
    if (i < C_OUT) b2f[i] = ldf(b2, i, isbf);
}

// ---------------- GEMM1: 128x128 tile, bf16 out ----------------
__global__ __launch_bounds__(256) void k_gemm128(
    const u16* __restrict__ xdir, const u16* __restrict__ xcvt,
    const int* __restrict__ flags, const u16* __restrict__ Bt,
    u16* __restrict__ C, int M, int K, int ldc) {
    const u16* A = flags[1] ? xdir : xcvt;
    __shared__ __align__(16) u16 As[128 * 32];
    __shared__ __align__(16) u16 Bs[128 * 32];
    int tid = threadIdx.x;
    int wave = tid >> 6, lane = tid & 63;
    int quad = lane >> 4, lrow = lane & 15;
    int wrow = (wave & 1) * 64, wcol = (wave >> 1) * 64;
    int row0 = blockIdx.x * 128;
    int n0 = blockIdx.y * 128;
    int srow = tid >> 1;
    int scol = (tid & 1) * 16;

    f32x4 acc[4][4] = {};
    int kTiles = K >> 5;
    for (int kt = 0; kt < kTiles; ++kt) {
        int k0 = kt * 32;
        uint4 a0 = make_uint4(0, 0, 0, 0), a1 = make_uint4(0, 0, 0, 0);
        int gr = row0 + srow;
        if (gr < M) {
            const u16* ap = A + (size_t)gr * K + k0 + scol;
            a0 = *(const uint4*)ap;
            a1 = *(const uint4*)(ap + 8);
        }
        const u16* bp = Bt + (size_t)(n0 + srow) * K + k0 + scol;
        uint4 b0 = *(const uint4*)bp;
        uint4 b1 = *(const uint4*)(bp + 8);
        __syncthreads();
        *(uint4*)(As + srow * 32 + scol) = a0;
        *(uint4*)(As + srow * 32 + scol + 8) = a1;
        *(uint4*)(Bs + srow * 32 + scol) = b0;
        *(uint4*)(Bs + srow * 32 + scol + 8) = b1;
        __syncthreads();
        bf16x8 af[4], bfr[4];
#pragma unroll
        for (int i = 0; i < 4; ++i)
            af[i] = *(const bf16x8*)(As + (wrow + i * 16 + lrow) * 32 + quad * 8);
#pragma unroll
        for (int j = 0; j < 4; ++j)
            bfr[j] = *(const bf16x8*)(Bs + (wcol + j * 16 + lrow) * 32 + quad * 8);
#pragma unroll
        for (int i = 0; i < 4; ++i)
#pragma unroll
            for (int j = 0; j < 4; ++j)
                acc[i][j] = __builtin_amdgcn_mfma_f32_16x16x32_bf16(af[i], bfr[j],
                                                                    acc[i][j], 0, 0, 0);
    }
#pragma unroll
    for (int i = 0; i < 4; ++i)
#pragma unroll
        for (int j = 0; j < 4; ++j)
#pragma unroll
            for (int r = 0; r < 4; ++r) {
                int row = row0 + wrow + i * 16 + quad * 4 + r;
                int col = n0 + wcol + j * 16 + lrow;
                if (row < M) C[(size_t)row * ldc + col] = f2bf(acc[i][j][r]);
            }
}

// ---------------- GEMM2: 64x64 tile, fp32 out ----------------
__global__ __launch_bounds__(256) void k_gemm64(
    const u16* __restrict__ A, const u16* __restrict__ Bt, float* __restrict__ Cout,
    int M, int K, int Ncols, int ldc) {
    __shared__ __align__(16) u16 As[64 * 32];
    __shared__ __align__(16) u16 Bs[64 * 32];
    int tid = threadIdx.x;
    int wave = tid >> 6, lane = tid & 63;
    int quad = lane >> 4, lrow = lane & 15;
    int row0 = blockIdx.x * 64;
    int n0 = blockIdx.y * 64;
    int srow = tid >> 2;
    int skc = (tid & 3) * 8;

    f32x4 acc[4] = {};
    int kTiles = K >> 5;
    for (int kt = 0; kt < kTiles; ++kt) {
        int k0 = kt * 32;
        uint4 av = make_uint4(0, 0, 0, 0);
        int gr = row0 + srow;
        if (gr < M) av = *(const uint4*)(A + (size_t)gr * K + k0 + skc);
        uint4 bv = *(const uint4*)(Bt + (size_t)(n0 + srow) * K + k0 + skc);
        __syncthreads();
        *(uint4*)(As + srow * 32 + skc) = av;
        *(uint4*)(Bs + srow * 32 + skc) = bv;
        __syncthreads();
        bf16x8 af = *(const bf16x8*)(As + (wave * 16 + lrow) * 32 + quad * 8);
#pragma unroll
        for (int t = 0; t < 4; ++t) {
            bf16x8 bfr = *(const bf16x8*)(Bs + (t * 16 + lrow) * 32 + quad * 8);
            acc[t] = __builtin_amdgcn_mfma_f32_16x16x32_bf16(af, bfr, acc[t], 0, 0, 0);
        }
    }
#pragma unroll
    for (int t = 0; t < 4; ++t)
#pragma unroll
        for (int r = 0; r < 4; ++r) {
            int row = wave * 16 + quad * 4 + r;
            int col = t * 16 + lrow;
            int gr = row0 + row, gc = n0 + col;
            if (gr < M && gc < Ncols) Cout[(size_t)gr * ldc + gc] = acc[t][r];
        }
}

// ---------------- agg1: hagg = ReLU(Anorm*h + b1), bf16 in/out ----------------
__device__ __forceinline__ void accum8(float* acc, uint4 p, float w) {
    acc[0] += w * bf2f((u16)p.x); acc[1] += w * bf2f((u16)(p.x >> 16));
    acc[2] += w * bf2f((u16)p.y); acc[3] += w * bf2f((u16)(p.y >> 16));
    acc[4] += w * bf2f((u16)p.z); acc[5] += w * bf2f((u16)(p.z >> 16));
    acc[6] += w * bf2f((u16)p.w); acc[7] += w * bf2f((u16)(p.w >> 16));
}

__global__ __launch_bounds__(256) void k_agg1(
    const u16* __restrict__ h, const int* __restrict__ csr, const int* __restrict__ offs,
    const float* __restrict__ dinv, const float* __restrict__ b1f,
    u16* __restrict__ out, int n, int Etot, int nbk) {
    int wave = threadIdx.x >> 6, lane = threadIdx.x & 63;
    int v = blockIdx.x * 4 + wave;
    if (v >= n) return;
    float dv = dinv[v];
    float wself = dv * dv;

    float acc[8];
    uint4 hs = *(const uint4*)(h + (size_t)v * C_HID + lane * 8);
    acc[0] = wself * bf2f((u16)hs.x); acc[1] = wself * bf2f((u16)(hs.x >> 16));
    acc[2] = wself * bf2f((u16)hs.y); acc[3] = wself * bf2f((u16)(hs.y >> 16));
    acc[4] = wself * bf2f((u16)hs.z); acc[5] = wself * bf2f((u16)(hs.z >> 16));
    acc[6] = wself * bf2f((u16)hs.w); acc[7] = wself * bf2f((u16)(hs.w >> 16));

    int e0 = imax(0, imin(offs[v * nbk], Etot));
    int e1 = imax(e0, imin(offs[(v + 1) * nbk], Etot));
    for (int base = e0; base < e1; base += 64) {
        int cnt = imin(64, e1 - base);
        int sreg = 0; float wreg = 0.f;
        if (lane < cnt) {
            u32 s = (u32)csr[base + lane];
            s = (s < (u32)n) ? s : 0u;
            sreg = (int)s;
            wreg = dv * dinv[s];
        }
        int j = 0;
        for (; j + 8 <= cnt; j += 8) {
            int ss[8]; float ww[8]; uint4 pp[8];
#pragma unroll
            for (int t = 0; t < 8; ++t) {
                ss[t] = __shfl(sreg, j + t);
                ww[t] = __shfl(wreg, j + t);
            }
#pragma unroll
            for (int t = 0; t < 8; ++t)
                pp[t] = *(const uint4*)(h + (size_t)ss[t] * C_HID + lane * 8);
#pragma unroll
            for (int t = 0; t < 8; ++t) accum8(acc, pp[t], ww[t]);
        }
        for (; j + 2 <= cnt; j += 2) {
            int s0 = __shfl(sreg, j), s1 = __shfl(sreg, j + 1);
            float w0 = __shfl(wreg, j), w1 = __shfl(wreg, j + 1);
            uint4 p0 = *(const uint4*)(h + (size_t)s0 * C_HID + lane * 8);
            uint4 p1 = *(const uint4*)(h + (size_t)s1 * C_HID + lane * 8);
            accum8(acc, p0, w0); accum8(acc, p1, w1);
        }
        for (; j < cnt; ++j) {
            int sj = __shfl(sreg, j);
            float wj = __shfl(wreg, j);
            uint4 pj = *(const uint4*)(h + (size_t)sj * C_HID + lane * 8);
            accum8(acc, pj, wj);
        }
    }

    float4 ba = *(const float4*)(b1f + lane * 8);
    float4 bb = *(const float4*)(b1f + lane * 8 + 4);
    float r0 = fmaxf(acc[0] + ba.x, 0.f), r1 = fmaxf(acc[1] + ba.y, 0.f);
    float r2 = fmaxf(acc[2] + ba.z, 0.f), r3 = fmaxf(acc[3] + ba.w, 0.f);
    float r4 = fmaxf(acc[4] + bb.x, 0.f), r5 = fmaxf(acc[5] + bb.y, 0.f);
    float r6 = fmaxf(acc[6] + bb.z, 0.f), r7 = fmaxf(acc[7] + bb.w, 0.f);
    uint4 o;
    o.x = (u32)f2bf(r0) | ((u32)f2bf(r1) << 16);
    o.y = (u32)f2bf(r2) | ((u32)f2bf(r3) << 16);
    o.z = (u32)f2bf(r4) | ((u32)f2bf(r5) << 16);
    o.w = (u32)f2bf(r6) | ((u32)f2bf(r7) << 16);
    *(uint4*)(out + (size_t)v * C_HID + lane * 8) = o;
}

// ---------------- agg2 + bias + log_softmax ----------------
__global__ __launch_bounds__(256) void k_agg2(
    const float* __restrict__ h2, const int* __restrict__ csr, const int* __restrict__ offs,
    const float* __restrict__ dinv, const float* __restrict__ b2f,
    const int* __restrict__ flags, void* __restrict__ out, int n, int Etot, int nbk) {
    int wave = threadIdx.x >> 6, lane = threadIdx.x & 63;
    int v = blockIdx.x * 4 + wave;
    if (v >= n) return;
    float dv = dinv[v];
    float acc = 0.f;
    if (lane < C_OUT) acc = dv * dv * h2[(size_t)v * C_OUT + lane];

    int e0 = imax(0, imin(offs[v * nbk], Etot));
    int e1 = imax(e0, imin(offs[(v + 1) * nbk], Etot));
    int lidx = (lane < C_OUT) ? lane : 0;
    for (int base = e0; base < e1; base += 64) {
        int cnt = imin(64, e1 - base);
        int sreg = 0; float wreg = 0.f;
        if (lane < cnt) {
            u32 s = (u32)csr[base + lane];
            s = (s < (u32)n) ? s : 0u;
            sreg = (int)s;
            wreg = dv * dinv[s];
        }
        int j = 0;
        for (; j + 8 <= cnt; j += 8) {
            int ss[8]; float ww[8]; float pv[8];
#pragma unroll
            for (int t = 0; t < 8; ++t) {
                ss[t] = __shfl(sreg, j + t);
                ww[t] = __shfl(wreg, j + t);
            }
#pragma unroll
            for (int t = 0; t < 8; ++t) pv[t] = h2[(size_t)ss[t] * C_OUT + lidx];
            if (lane < C_OUT) {
#pragma unroll
                for (int t = 0; t < 8; ++t) acc += ww[t] * pv[t];
            }
        }
        for (; j < cnt; ++j) {
            int sj = __shfl(sreg, j);
            float wj = __shfl(wreg, j);
            float pj = h2[(size_t)sj * C_OUT + lidx];
            if (lane < C_OUT) acc += wj * pj;
        }
    }

    if (lane < C_OUT) acc += b2f[lane];
    float m = (lane < C_OUT) ? acc : -1e30f;
    for (int off = 32; off > 0; off >>= 1) m = fmaxf(m, __shfl_xor(m, off));
    float ex = (lane < C_OUT) ? expf(acc - m) : 0.f;
    float sum = ex;
    for (int off = 32; off > 0; off >>= 1) sum += __shfl_xor(sum, off);
    if (lane < C_OUT) {
        float r = acc - m - logf(sum);
        if (flags[1]) ((u16*)out)[(size_t)v * C_OUT + lane] = f2bf(r);
        else ((float*)out)[(size_t)v * C_OUT + lane] = r;
    }
}

// ---------------- launch ----------------

extern "C" void kernel_launch(void* const* d_in, const int* in_sizes, int n_in,
                              void* d_out, int out_size, void* d_ws, size_t ws_size,
                              hipStream_t stream) {
    const void* x = d_in[0];
    const int* ei = (const int*)d_in[1];
    const void* W1 = d_in[2];
    const void* b1 = d_in[3];
    const void* W2 = d_in[4];
    const void* b2 = d_in[5];

    const int N = out_size / C_OUT;
    const int Mx = in_sizes[0] / C_IN;
    const int M = (N < Mx) ? N : Mx;
    const int ECAP = in_sizes[1];
    const int E = ECAP / 2;
    const int nbk = (N + (1 << BSHIFT) - 1) >> BSHIFT;   // src buckets (25 @ 50k)
    const int KN = N * nbk;                              // key space

    char* p = (char*)d_ws;
    size_t used = 0;
    auto carve = [&](size_t bytes) -> void* {
        void* r = (void*)p;
        size_t b = (bytes + 255) & ~(size_t)255;
        p += b; used += b;
        return r;
    };
    int* flags = (int*)carve(256);
    float* dinv = (float*)carve((size_t)N * 4);
    int* offs = (int*)carve((size_t)(KN + 1) * 4);
    int* count = (int*)carve((size_t)KN * 4);     // reused as cursor
    int* bs0 = (int*)carve(32768);
    int* bs1 = (int*)carve(1024);
    int* csr = (int*)carve((size_t)E * 4);
    u16* w1t = (u16*)carve((size_t)C_HID * C_IN * 2);
    u16* w2t = (u16*)carve((size_t)64 * C_HID * 2);
    float* b1f = (float*)carve(C_HID * 4);
    float* b2f = (float*)carve(256);
    u16* bufA = (u16*)carve((size_t)N * C_HID * 2);
    u16* bufB = (u16*)carve((size_t)N * C_HID * 2);
    if (used > ws_size) return;

    u16* xcvt = bufA;
    u16* hbf = bufB;
    u16* hagg = bufA;
    float* h2 = (float*)bufB;

    const int EB = (E + 255) / 256;
    const int KB = (KN + 255) / 256;       // 4883 @ 50k
    const int KB2 = (KB + 255) / 256;      // 20

    k_detect<<<1, 64, 0, stream>>>((const u32*)x, ei, flags);

    // bucketed CSR build
    k_zero<<<KB, 256, 0, stream>>>(count, KN);
    k_count<<<EB, 256, 0, stream>>>(ei, flags, count, E, ECAP, N, nbk);
    k_blksum<<<KB, 256, 0, stream>>>(count, bs0, KN);
    k_blksum<<<KB2, 256, 0, stream>>>(bs0, bs1, KB);
    k_scansmall<<<1, 64, 0, stream>>>(bs1, KB2, offs + KN);
    k_scanadd<<<KB2, 256, 0, stream>>>(bs0, bs1, bs0, KB);
    k_scanadd<<<KB, 256, 0, stream>>>(count, bs0, offs, KN);
    k_zero<<<KB, 256, 0, stream>>>(count, KN);   // now cursor
    k_place<<<EB, 256, 0, stream>>>(ei, flags, offs, count, csr, E, ECAP, N, nbk);
    k_dinv<<<(N + 255) / 256, 256, 0, stream>>>(offs, dinv, N, nbk);

    k_convx<<<(M * C_IN + 255) / 256, 256, 0, stream>>>(x, flags, xcvt, M * C_IN);
    k_w1t<<<(C_IN * C_HID) / 256, 256, 0, stream>>>(W1, flags, w1t);
    k_w2t<<<(64 * C_HID) / 256, 256, 0, stream>>>(W2, flags, w2t);
    k_bias<<<2, 256, 0, stream>>>(b1, b2, flags, b1f, b2f);

    dim3 g1((M + 127) / 128, C_HID / 128);
    k_gemm128<<<g1, 256, 0, stream>>>((const u16*)x, xcvt, flags, w1t, hbf,
                                      M, C_IN, C_HID);

    k_agg1<<<(N + 3) / 4, 256, 0, stream>>>(hbf, csr, offs, dinv, b1f, hagg, N, E, nbk);

    dim3 g2((N + 63) / 64, 1);
    k_gemm64<<<g2, 256, 0, stream>>>(hagg, w2t, h2, N, C_HID, C_OUT, C_OUT);

    k_agg2<<<(N + 3) / 4, 256, 0, stream>>>(h2, csr, offs, dinv, b2f, flags, d_out, N, E, nbk);
}

// Round 8
// 522.013 us; speedup vs baseline: 1.2846x; 1.0193x over previous
//
#include <hip/hip_runtime.h>

// GCN 2-layer forward on gfx950.
// R8: agg kernels get __launch_bounds__(256,4) so the unroll-8 gather pipeline
//     actually fits in registers (R6/R7 had VGPR=44 -> serialized loads);
//     GEMM1 staged via global_load_lds width=16 (m97 ladder step);
//     simple dst-CSR build restored; k_detect parallelized.

typedef unsigned int u32;
typedef unsigned short u16;
typedef __bf16 bf16x8 __attribute__((ext_vector_type(8)));
typedef float f32x4 __attribute__((ext_vector_type(4)));

#define C_IN 512
#define C_HID 512
#define C_OUT 40

__device__ __forceinline__ float bf2f(u16 u) {
    u32 x = ((u32)u) << 16;
    return __builtin_bit_cast(float, x);
}
__device__ __forceinline__ u16 f2bf(float f) {
    u32 x = __builtin_bit_cast(u32, f);
    x += 0x7fffu + ((x >> 16) & 1u);   // RNE
    return (u16)(x >> 16);
}
__host__ __device__ __forceinline__ int imin(int a, int b) { return a < b ? a : b; }
__host__ __device__ __forceinline__ int imax(int a, int b) { return a > b ? a : b; }

// ---------------- dtype detection (one wave, ballot-reduced) ----------------
__global__ void k_detect(const u32* __restrict__ x32, const int* __restrict__ ei,
                         int* flags) {
    int lane = threadIdx.x & 63;
    int z = (ei[2 * lane + 1] == 0) ? 1 : 0;      // int64 indices -> odd words 0
    u32 e = (x32[lane] >> 7) & 0xff;               // bf16 exponent if packed
    int v = (e >= 110 && e <= 133) ? 1 : 0;
    unsigned long long bz = __ballot(z);
    unsigned long long bv = __ballot(v);
    if (threadIdx.x == 0) {
        flags[0] = (__popcll(bz) == 64) ? 2 : 1;   // int32 step per edge element
        flags[1] = (__popcll(bv) >= 48) ? 1 : 0;   // floats bf16-packed?
    }
}

// ---------------- graph preprocessing (simple dst-CSR) ----------------

__global__ void k_init(int* deg, int* cursor, int n) {
    int i = blockIdx.x * 256 + threadIdx.x;
    if (i < n) { deg[i] = 1; cursor[i] = 0; }   // self-loop
}

__global__ void k_deg(const int* __restrict__ ei, const int* __restrict__ flags,
                      int* deg, int E, int ecap, int n) {
    int e = blockIdx.x * 256 + threadIdx.x;
    if (e >= E) return;
    int st = flags[0];
    int cap = ecap * st - 1;
    u32 d = (u32)ei[imin((E + e) * st, cap)];
    if (d < (u32)n) atomicAdd(&deg[d], 1);
}

__global__ void k_dinv(const int* __restrict__ deg, float* dinv, int n) {
    int i = blockIdx.x * 256 + threadIdx.x;
    if (i < n) dinv[i] = rsqrtf((float)imax(deg[i], 1));
}

__global__ void k_scanA(const int* __restrict__ deg, int* bsum, int n) {
    __shared__ int sh[256];
    int i = blockIdx.x * 256 + threadIdx.x;
    sh[threadIdx.x] = (i < n) ? deg[i] - 1 : 0;
    __syncthreads();
    for (int d = 128; d > 0; d >>= 1) {
        if (threadIdx.x < d) sh[threadIdx.x] += sh[threadIdx.x + d];
        __syncthreads();
    }
    if (threadIdx.x == 0) bsum[blockIdx.x] = sh[0];
}

__global__ void k_scanB(int* bsum, int nb, int* offs, int n) {
    if (threadIdx.x == 0 && blockIdx.x == 0) {
        int run = 0;
        for (int b = 0; b < nb; ++b) { int t = bsum[b]; bsum[b] = run; run += t; }
        offs[n] = run;
    }
}

__global__ void k_scanC(const int* __restrict__ deg, const int* __restrict__ bsum,
                        int* offs, int n) {
    __shared__ int sh[256];
    int t = threadIdx.x;
    int i = blockIdx.x * 256 + t;
    int v = (i < n) ? deg[i] - 1 : 0;
    sh[t] = v;
    __syncthreads();
    for (int d = 1; d < 256; d <<= 1) {
        int add = (t >= d) ? sh[t - d] : 0;
        __syncthreads();
        sh[t] += add;
        __syncthreads();
    }
    if (i < n) offs[i] = bsum[blockIdx.x] + sh[t] - v;
}

__global__ void k_sort(const int* __restrict__ ei, const int* __restrict__ flags,
                       const int* __restrict__ offs, int* cursor, int* csr,
                       int E, int ecap, int n) {
    int e = blockIdx.x * 256 + threadIdx.x;
    if (e >= E) return;
    int st = flags[0];
    int cap = ecap * st - 1;
    u32 d = (u32)ei[imin((E + e) * st, cap)];
    u32 s = (u32)ei[imin(e * st, cap)];
    if (d < (u32)n && s < (u32)n) {
        int pos = offs[d] + atomicAdd(&cursor[(int)d], 1);
        if ((u32)pos < (u32)E) csr[pos] = (int)s;
    }
}

// ---------------- conversions ----------------

__device__ __forceinline__ float ldf(const void* p, int i, int isbf) {
    return isbf ? bf2f(((const u16*)p)[i]) : ((const float*)p)[i];
}

__global__ void k_convx(const void* __restrict__ x, const int* __restrict__ flags,
                        u16* __restrict__ out, int nelem) {
    if (flags[1]) return;   // bf16 x consumed directly
    int i = blockIdx.x * 256 + threadIdx.x;
    if (i >= nelem) return;
    out[i] = f2bf(((const float*)x)[i]);
}

__global__ void k_w1t(const void* __restrict__ W, const int* __restrict__ flags,
                      u16* __restrict__ out) {
    int id = blockIdx.x * 256 + threadIdx.x;
    int n = id >> 9, k = id & 511;
    out[n * 512 + k] = f2bf(ldf(W, k * 512 + n, flags[1]));
}

__global__ void k_w2t(const void* __restrict__ W, const int* __restrict__ flags,
                      u16* __restrict__ out) {
    int id = blockIdx.x * 256 + threadIdx.x;
    int n = id >> 9, k = id & 511;
    out[id] = (n < C_OUT) ? f2bf(ldf(W, k * C_OUT + n, flags[1])) : (u16)0;
}

__global__ void k_bias(const void* __restrict__ b1, const void* __restrict__ b2,
                       const int* __restrict__ flags, float* __restrict__ b1f,
                       float* __restrict__ b2f) {
    int i = threadIdx.x + blockIdx.x * 256;
    int isbf = flags[1];
    if (i < C_HID) b1f[i] = ldf(b1, i, isbf);
    if (i < C_OUT) b2f[i] = ldf(b2, i, isbf);
}

// ---------------- GEMM1: 128x128 tile, global_load_lds staging (m97) ----------------
// Each wave stages 32 rows of As and Bs via 2+2 global_load_lds_dwordx4
// (wave-uniform LDS base + lane*16B == row-major 16 rows x 64B). A-rows clamped
// to M-1 on the ragged last block row (garbage only reaches masked C rows).
typedef __attribute__((address_space(1))) const u32 glds_src;
typedef __attribute__((address_space(3))) u32 glds_dst;

__global__ __launch_bounds__(256) void k_gemm128(
    const u16* __restrict__ xdir, const u16* __restrict__ xcvt,
    const int* __restrict__ flags, const u16* __restrict__ Bt,
    u16* __restrict__ C, int M, int K, int ldc) {
    const u16* A = flags[1] ? xdir : xcvt;
    __shared__ __align__(16) u16 As[128 * 32];
    __shared__ __align__(16) u16 Bs[128 * 32];
    int tid = threadIdx.x;
    int wave = tid >> 6, lane = tid & 63;
    int quad = lane >> 4, lrow = lane & 15;
    int wrow = (wave & 1) * 64, wcol = (wave >> 1) * 64;
    int row0 = blockIdx.x * 128;
    int n0 = blockIdx.y * 128;

    int lr = lane >> 2;           // row within 16-row staging group
    int lc = (lane & 3) * 8;      // element col offset 0,8,16,24
    int ar = row0 + wave * 32 + lr;
    int br = n0 + wave * 32 + lr;
    u16* As_w = As + (wave * 32) * 32;   // wave-uniform LDS base
    u16* Bs_w = Bs + (wave * 32) * 32;

    f32x4 acc[4][4] = {};
    int kTiles = K >> 5;
    for (int kt = 0; kt < kTiles; ++kt) {
        int k0 = kt * 32;
        int a0 = imin(ar, M - 1);
        int a1 = imin(ar + 16, M - 1);
        const u16* ga0 = A + (size_t)a0 * K + k0 + lc;
        const u16* ga1 = A + (size_t)a1 * K + k0 + lc;
        const u16* gb0 = Bt + (size_t)br * K + k0 + lc;
        const u16* gb1 = Bt + (size_t)(br + 16) * K + k0 + lc;
        __builtin_amdgcn_global_load_lds((glds_src*)ga0, (glds_dst*)As_w, 16, 0, 0);
        __builtin_amdgcn_global_load_lds((glds_src*)ga1, (glds_dst*)(As_w + 16 * 32), 16, 0, 0);
        __builtin_amdgcn_global_load_lds((glds_src*)gb0, (glds_dst*)Bs_w, 16, 0, 0);
        __builtin_amdgcn_global_load_lds((glds_src*)gb1, (glds_dst*)(Bs_w + 16 * 32), 16, 0, 0);
        __syncthreads();
        bf16x8 af[4], bfr[4];
#pragma unroll
        for (int i = 0; i < 4; ++i)
            af[i] = *(const bf16x8*)(As + (wrow + i * 16 + lrow) * 32 + quad * 8);
#pragma unroll
        for (int j = 0; j < 4; ++j)
            bfr[j] = *(const bf16x8*)(Bs + (wcol + j * 16 + lrow) * 32 + quad * 8);
#pragma unroll
        for (int i = 0; i < 4; ++i)
#pragma unroll
            for (int j = 0; j < 4; ++j)
                acc[i][j] = __builtin_amdgcn_mfma_f32_16x16x32_bf16(af[i], bfr[j],
                                                                    acc[i][j], 0, 0, 0);
        __syncthreads();
    }
#pragma unroll
    for (int i = 0; i < 4; ++i)
#pragma unroll
        for (int j = 0; j < 4; ++j)
#pragma unroll
            for (int r = 0; r < 4; ++r) {
                int row = row0 + wrow + i * 16 + quad * 4 + r;
                int col = n0 + wcol + j * 16 + lrow;
                if (row < M) C[(size_t)row * ldc + col] = f2bf(acc[i][j][r]);
            }
}

// ---------------- GEMM2: 64x64 tile, fp32 out ----------------
__global__ __launch_bounds__(256) void k_gemm64(
    const u16* __restrict__ A, const u16* __restrict__ Bt, float* __restrict__ Cout,
    int M, int K, int Ncols, int ldc) {
    __shared__ __align__(16) u16 As[64 * 32];
    __shared__ __align__(16) u16 Bs[64 * 32];
    int tid = threadIdx.x;
    int wave = tid >> 6, lane = tid & 63;
    int quad = lane >> 4, lrow = lane & 15;
    int row0 = blockIdx.x * 64;
    int n0 = blockIdx.y * 64;
    int srow = tid >> 2;
    int skc = (tid & 3) * 8;

    f32x4 acc[4] = {};
    int kTiles = K >> 5;
    for (int kt = 0; kt < kTiles; ++kt) {
        int k0 = kt * 32;
        uint4 av = make_uint4(0, 0, 0, 0);
        int gr = row0 + srow;
        if (gr < M) av = *(const uint4*)(A + (size_t)gr * K + k0 + skc);
        uint4 bv = *(const uint4*)(Bt + (size_t)(n0 + srow) * K + k0 + skc);
        __syncthreads();
        *(uint4*)(As + srow * 32 + skc) = av;
        *(uint4*)(Bs + srow * 32 + skc) = bv;
        __syncthreads();
        bf16x8 af = *(const bf16x8*)(As + (wave * 16 + lrow) * 32 + quad * 8);
#pragma unroll
        for (int t = 0; t < 4; ++t) {
            bf16x8 bfr = *(const bf16x8*)(Bs + (t * 16 + lrow) * 32 + quad * 8);
            acc[t] = __builtin_amdgcn_mfma_f32_16x16x32_bf16(af, bfr, acc[t], 0, 0, 0);
        }
    }
#pragma unroll
    for (int t = 0; t < 4; ++t)
#pragma unroll
        for (int r = 0; r < 4; ++r) {
            int row = wave * 16 + quad * 4 + r;
            int col = t * 16 + lrow;
            int gr = row0 + row, gc = n0 + col;
            if (gr < M && gc < Ncols) Cout[(size_t)gr * ldc + gc] = acc[t][r];
        }
}

// ---------------- agg1: hagg = ReLU(Anorm*h + b1), bf16 in/out ----------------
// wave-per-node; launch_bounds(256,4) caps occupancy at 16 waves/CU so the
// compiler has ~128 VGPRs to keep all 8 gathers of the unroll in flight.
__device__ __forceinline__ void accum8(float* acc, uint4 p, float w) {
    acc[0] += w * bf2f((u16)p.x); acc[1] += w * bf2f((u16)(p.x >> 16));
    acc[2] += w * bf2f((u16)p.y); acc[3] += w * bf2f((u16)(p.y >> 16));
    acc[4] += w * bf2f((u16)p.z); acc[5] += w * bf2f((u16)(p.z >> 16));
    acc[6] += w * bf2f((u16)p.w); acc[7] += w * bf2f((u16)(p.w >> 16));
}

__global__ __launch_bounds__(256, 4) void k_agg1(
    const u16* __restrict__ h, const int* __restrict__ csr, const int* __restrict__ offs,
    const float* __restrict__ dinv, const float* __restrict__ b1f,
    u16* __restrict__ out, int n, int Etot) {
    int wave = threadIdx.x >> 6, lane = threadIdx.x & 63;
    int v = blockIdx.x * 4 + wave;
    if (v >= n) return;
    float dv = dinv[v];
    float wself = dv * dv;

    float acc[8];
    uint4 hs = *(const uint4*)(h + (size_t)v * C_HID + lane * 8);
    acc[0] = wself * bf2f((u16)hs.x); acc[1] = wself * bf2f((u16)(hs.x >> 16));
    acc[2] = wself * bf2f((u16)hs.y); acc[3] = wself * bf2f((u16)(hs.y >> 16));
    acc[4] = wself * bf2f((u16)hs.z); acc[5] = wself * bf2f((u16)(hs.z >> 16));
    acc[6] = wself * bf2f((u16)hs.w); acc[7] = wself * bf2f((u16)(hs.w >> 16));

    int e0 = imax(0, imin(offs[v], Etot));
    int e1 = imax(e0, imin(offs[v + 1], Etot));
    for (int base = e0; base < e1; base += 64) {
        int cnt = imin(64, e1 - base);
        int sreg = 0; float wreg = 0.f;
        if (lane < cnt) {
            u32 s = (u32)csr[base + lane];
            s = (s < (u32)n) ? s : 0u;
            sreg = (int)s;
            wreg = dv * dinv[s];
        }
        int j = 0;
        for (; j + 8 <= cnt; j += 8) {
            int ss[8]; float ww[8]; uint4 pp[8];
#pragma unroll
            for (int t = 0; t < 8; ++t) {
                ss[t] = __shfl(sreg, j + t);
                ww[t] = __shfl(wreg, j + t);
            }
#pragma unroll
            for (int t = 0; t < 8; ++t)
                pp[t] = *(const uint4*)(h + (size_t)ss[t] * C_HID + lane * 8);
#pragma unroll
            for (int t = 0; t < 8; ++t) accum8(acc, pp[t], ww[t]);
        }
        for (; j + 2 <= cnt; j += 2) {
            int s0 = __shfl(sreg, j), s1 = __shfl(sreg, j + 1);
            float w0 = __shfl(wreg, j), w1 = __shfl(wreg, j + 1);
            uint4 p0 = *(const uint4*)(h + (size_t)s0 * C_HID + lane * 8);
            uint4 p1 = *(const uint4*)(h + (size_t)s1 * C_HID + lane * 8);
            accum8(acc, p0, w0); accum8(acc, p1, w1);
        }
        for (; j < cnt; ++j) {
            int sj = __shfl(sreg, j);
            float wj = __shfl(wreg, j);
            uint4 pj = *(const uint4*)(h + (size_t)sj * C_HID + lane * 8);
            accum8(acc, pj, wj);
        }
    }

    float4 ba = *(const float4*)(b1f + lane * 8);
    float4 bb = *(const float4*)(b1f + lane * 8 + 4);
    float r0 = fmaxf(acc[0] + ba.x, 0.f), r1 = fmaxf(acc[1] + ba.y, 0.f);
    float r2 = fmaxf(acc[2] + ba.z, 0.f), r3 = fmaxf(acc[3] + ba.w, 0.f);
    float r4 = fmaxf(acc[4] + bb.x, 0.f), r5 = fmaxf(acc[5] + bb.y, 0.f);
    float r6 = fmaxf(acc[6] + bb.z, 0.f), r7 = fmaxf(acc[7] + bb.w, 0.f);
    uint4 o;
    o.x = (u32)f2bf(r0) | ((u32)f2bf(r1) << 16);
    o.y = (u32)f2bf(r2) | ((u32)f2bf(r3) << 16);
    o.z = (u32)f2bf(r4) | ((u32)f2bf(r5) << 16);
    o.w = (u32)f2bf(r6) | ((u32)f2bf(r7) << 16);
    *(uint4*)(out + (size_t)v * C_HID + lane * 8) = o;
}

// ---------------- agg2 + bias + log_softmax ----------------
__global__ __launch_bounds__(256, 4) void k_agg2(
    const float* __restrict__ h2, const int* __restrict__ csr, const int* __restrict__ offs,
    const float* __restrict__ dinv, const float* __restrict__ b2f,
    const int* __restrict__ flags, void* __restrict__ out, int n, int Etot) {
    int wave = threadIdx.x >> 6, lane = threadIdx.x & 63;
    int v = blockIdx.x * 4 + wave;
    if (v >= n) return;
    float dv = dinv[v];
    float acc = 0.f;
    if (lane < C_OUT) acc = dv * dv * h2[(size_t)v * C_OUT + lane];

    int e0 = imax(0, imin(offs[v], Etot));
    int e1 = imax(e0, imin(offs[v + 1], Etot));
    int lidx = (lane < C_OUT) ? lane : 0;
    for (int base = e0; base < e1; base += 64) {
        int cnt = imin(64, e1 - base);
        int sreg = 0; float wreg = 0.f;
        if (lane < cnt) {
            u32 s = (u32)csr[base + lane];
            s = (s < (u32)n) ? s : 0u;
            sreg = (int)s;
            wreg = dv * dinv[s];
        }
        int j = 0;
        for (; j + 8 <= cnt; j += 8) {
            int ss[8]; float ww[8]; float pv[8];
#pragma unroll
            for (int t = 0; t < 8; ++t) {
                ss[t] = __shfl(sreg, j + t);
                ww[t] = __shfl(wreg, j + t);
            }
#pragma unroll
            for (int t = 0; t < 8; ++t) pv[t] = h2[(size_t)ss[t] * C_OUT + lidx];
            if (lane < C_OUT) {
#pragma unroll
                for (int t = 0; t < 8; ++t) acc += ww[t] * pv[t];
            }
        }
        for (; j < cnt; ++j) {
            int sj = __shfl(sreg, j);
            float wj = __shfl(wreg, j);
            float pj = h2[(size_t)sj * C_OUT + lidx];
            if (lane < C_OUT) acc += wj * pj;
        }
    }

    if (lane < C_OUT) acc += b2f[lane];
    float m = (lane < C_OUT) ? acc : -1e30f;
    for (int off = 32; off > 0; off >>= 1) m = fmaxf(m, __shfl_xor(m, off));
    float ex = (lane < C_OUT) ? expf(acc - m) : 0.f;
    float sum = ex;
    for (int off = 32; off > 0; off >>= 1) sum += __shfl_xor(sum, off);
    if (lane < C_OUT) {
        float r = acc - m - logf(sum);
        if (flags[1]) ((u16*)out)[(size_t)v * C_OUT + lane] = f2bf(r);
        else ((float*)out)[(size_t)v * C_OUT + lane] = r;
    }
}

// ---------------- launch ----------------

extern "C" void kernel_launch(void* const* d_in, const int* in_sizes, int n_in,
                              void* d_out, int out_size, void* d_ws, size_t ws_size,
                              hipStream_t stream) {
    const void* x = d_in[0];
    const int* ei = (const int*)d_in[1];
    const void* W1 = d_in[2];
    const void* b1 = d_in[3];
    const void* W2 = d_in[4];
    const void* b2 = d_in[5];

    const int N = out_size / C_OUT;
    const int Mx = in_sizes[0] / C_IN;
    const int M = (N < Mx) ? N : Mx;
    const int ECAP = in_sizes[1];
    const int E = ECAP / 2;

    char* p = (char*)d_ws;
    size_t used = 0;
    auto carve = [&](size_t bytes) -> void* {
        void* r = (void*)p;
        size_t b = (bytes + 255) & ~(size_t)255;
        p += b; used += b;
        return r;
    };
    int* flags = (int*)carve(256);
    int* deg = (int*)carve((size_t)N * 4);
    int* cursor = (int*)carve((size_t)N * 4);
    float* dinv = (float*)carve((size_t)N * 4);
    int* offs = (int*)carve((size_t)(N + 1) * 4);
    int* bsum = (int*)carve(8192);
    int* csr = (int*)carve((size_t)E * 4);
    u16* w1t = (u16*)carve((size_t)C_HID * C_IN * 2);
    u16* w2t = (u16*)carve((size_t)64 * C_HID * 2);
    float* b1f = (float*)carve(C_HID * 4);
    float* b2f = (float*)carve(256);
    u16* bufA = (u16*)carve((size_t)N * C_HID * 2);   // xcvt (fp32 case), then hagg
    u16* bufB = (u16*)carve((size_t)N * C_HID * 2);   // hbf, then h2 (fp32)
    if (used > ws_size) return;

    u16* xcvt = bufA;
    u16* hbf = bufB;
    u16* hagg = bufA;
    float* h2 = (float*)bufB;

    const int NB = (N + 255) / 256;
    const int EB = (E + 255) / 256;

    k_detect<<<1, 64, 0, stream>>>((const u32*)x, ei, flags);

    k_init<<<NB, 256, 0, stream>>>(deg, cursor, N);
    k_deg<<<EB, 256, 0, stream>>>(ei, flags, deg, E, ECAP, N);
    k_dinv<<<NB, 256, 0, stream>>>(deg, dinv, N);
    k_scanA<<<NB, 256, 0, stream>>>(deg, bsum, N);
    k_scanB<<<1, 64, 0, stream>>>(bsum, NB, offs, N);
    k_scanC<<<NB, 256, 0, stream>>>(deg, bsum, offs, N);
    k_sort<<<EB, 256, 0, stream>>>(ei, flags, offs, cursor, csr, E, ECAP, N);

    k_convx<<<(M * C_IN + 255) / 256, 256, 0, stream>>>(x, flags, xcvt, M * C_IN);
    k_w1t<<<(C_IN * C_HID) / 256, 256, 0, stream>>>(W1, flags, w1t);
    k_w2t<<<(64 * C_HID) / 256, 256, 0, stream>>>(W2, flags, w2t);
    k_bias<<<2, 256, 0, stream>>>(b1, b2, flags, b1f, b2f);

    dim3 g1((M + 127) / 128, C_HID / 128);
    k_gemm128<<<g1, 256, 0, stream>>>((const u16*)x, xcvt, flags, w1t, hbf,
                                      M, C_IN, C_HID);

    k_agg1<<<(N + 3) / 4, 256, 0, stream>>>(hbf, csr, offs, dinv, b1f, hagg, N, E);

    dim3 g2((N + 63) / 64, 1);
    k_gemm64<<<g2, 256, 0, stream>>>(hagg, w2t, h2, N, C_HID, C_OUT, C_OUT);

    k_agg2<<<(N + 3) / 4, 256, 0, stream>>>(h2, csr, offs, dinv, b2f, flags, d_out, N, E);
}

// Round 9
// 492.661 us; speedup vs baseline: 1.3612x; 1.0596x over previous
//
#include <hip/hip_runtime.h>

// GCN 2-layer forward on gfx950.
// R9: dispatch-count cut 16->11 (detect->init, dinv->scanA, convx/w1t/w2t/bias
//     -> one grid-stride k_prep); agg2 rewritten to 6-edges-per-wave float4
//     gathers + cross-group shfl reduce. agg1 is at its gather roofline
//     (~121us, 3.8 TB/s beyond-L2, FETCH 8x footprint) and is unchanged.

typedef unsigned int u32;
typedef unsigned short u16;
typedef __bf16 bf16x8 __attribute__((ext_vector_type(8)));
typedef float f32x4 __attribute__((ext_vector_type(4)));

#define C_IN 512
#define C_HID 512
#define C_OUT 40

__device__ __forceinline__ float bf2f(u16 u) {
    u32 x = ((u32)u) << 16;
    return __builtin_bit_cast(float, x);
}
__device__ __forceinline__ u16 f2bf(float f) {
    u32 x = __builtin_bit_cast(u32, f);
    x += 0x7fffu + ((x >> 16) & 1u);   // RNE
    return (u16)(x >> 16);
}
__host__ __device__ __forceinline__ int imin(int a, int b) { return a < b ? a : b; }
__host__ __device__ __forceinline__ int imax(int a, int b) { return a > b ? a : b; }

// ---------------- init + dtype detect (fused) ----------------
__global__ void k_init(const u32* __restrict__ x32, const int* __restrict__ ei,
                       int* flags, int* deg, int* cursor, int n) {
    if (blockIdx.x == 0 && threadIdx.x < 64) {
        int lane = threadIdx.x;
        int z = (ei[2 * lane + 1] == 0) ? 1 : 0;      // int64 -> odd words are 0
        u32 e = (x32[lane] >> 7) & 0xff;               // bf16 exponent if packed
        int v = (e >= 110 && e <= 133) ? 1 : 0;
        unsigned long long bz = __ballot(z);
        unsigned long long bv = __ballot(v);
        if (lane == 0) {
            flags[0] = (__popcll(bz) == 64) ? 2 : 1;   // int32 step per element
            flags[1] = (__popcll(bv) >= 48) ? 1 : 0;   // floats bf16-packed?
        }
    }
    int i = blockIdx.x * 256 + threadIdx.x;
    if (i < n) { deg[i] = 1; cursor[i] = 0; }          // self-loop
}

__global__ void k_deg(const int* __restrict__ ei, const int* __restrict__ flags,
                      int* deg, int E, int ecap, int n) {
    int e = blockIdx.x * 256 + threadIdx.x;
    if (e >= E) return;
    int st = flags[0];
    int cap = ecap * st - 1;
    u32 d = (u32)ei[imin((E + e) * st, cap)];
    if (d < (u32)n) atomicAdd(&deg[d], 1);
}

// block sums of (deg-1) + dinv (fused)
__global__ void k_scanA(const int* __restrict__ deg, int* bsum, float* dinv, int n) {
    __shared__ int sh[256];
    int i = blockIdx.x * 256 + threadIdx.x;
    int dv = (i < n) ? deg[i] : 1;
    if (i < n) dinv[i] = rsqrtf((float)imax(dv, 1));
    sh[threadIdx.x] = (i < n) ? dv - 1 : 0;
    __syncthreads();
    for (int d = 128; d > 0; d >>= 1) {
        if (threadIdx.x < d) sh[threadIdx.x] += sh[threadIdx.x + d];
        __syncthreads();
    }
    if (threadIdx.x == 0) bsum[blockIdx.x] = sh[0];
}

__global__ void k_scanB(int* bsum, int nb, int* offs, int n) {
    if (threadIdx.x == 0 && blockIdx.x == 0) {
        int run = 0;
        for (int b = 0; b < nb; ++b) { int t = bsum[b]; bsum[b] = run; run += t; }
        offs[n] = run;
    }
}

__global__ void k_scanC(const int* __restrict__ deg, const int* __restrict__ bsum,
                        int* offs, int n) {
    __shared__ int sh[256];
    int t = threadIdx.x;
    int i = blockIdx.x * 256 + t;
    int v = (i < n) ? deg[i] - 1 : 0;
    sh[t] = v;
    __syncthreads();
    for (int d = 1; d < 256; d <<= 1) {
        int add = (t >= d) ? sh[t - d] : 0;
        __syncthreads();
        sh[t] += add;
        __syncthreads();
    }
    if (i < n) offs[i] = bsum[blockIdx.x] + sh[t] - v;
}

__global__ void k_sort(const int* __restrict__ ei, const int* __restrict__ flags,
                       const int* __restrict__ offs, int* cursor, int* csr,
                       int E, int ecap, int n) {
    int e = blockIdx.x * 256 + threadIdx.x;
    if (e >= E) return;
    int st = flags[0];
    int cap = ecap * st - 1;
    u32 d = (u32)ei[imin((E + e) * st, cap)];
    u32 s = (u32)ei[imin(e * st, cap)];
    if (d < (u32)n && s < (u32)n) {
        int pos = offs[d] + atomicAdd(&cursor[(int)d], 1);
        if ((u32)pos < (u32)E) csr[pos] = (int)s;
    }
}

// ---------------- fused prep: w1t + w2t + bias + (convx if fp32) ----------------
__device__ __forceinline__ float ldf(const void* p, int i, int isbf) {
    return isbf ? bf2f(((const u16*)p)[i]) : ((const float*)p)[i];
}

__global__ __launch_bounds__(256) void k_prep(
    const void* __restrict__ x, const void* __restrict__ W1, const void* __restrict__ b1,
    const void* __restrict__ W2, const void* __restrict__ b2,
    const int* __restrict__ flags, u16* __restrict__ w1t, u16* __restrict__ w2t,
    float* __restrict__ b1f, float* __restrict__ b2f, u16* __restrict__ xcvt,
    int nx) {
    int isbf = flags[1];
    int stride = gridDim.x * 256;
    int i0 = blockIdx.x * 256 + threadIdx.x;
    for (int i = i0; i < 512 * 512; i += stride) {
        int n = i >> 9, k = i & 511;
        w1t[n * 512 + k] = f2bf(ldf(W1, k * 512 + n, isbf));
    }
    for (int i = i0; i < 64 * 512; i += stride) {
        int n = i >> 9, k = i & 511;
        w2t[i] = (n < C_OUT) ? f2bf(ldf(W2, k * C_OUT + n, isbf)) : (u16)0;
    }
    if (i0 < C_HID) b1f[i0] = ldf(b1, i0, isbf);
    if (i0 < C_OUT) b2f[i0] = ldf(b2, i0, isbf);
    if (!isbf) {
        for (int i = i0; i < nx; i += stride)
            xcvt[i] = f2bf(((const float*)x)[i]);
    }
}

// ---------------- GEMM1: 128x128 tile, global_load_lds staging (m97) ----------------
typedef __attribute__((address_space(1))) const u32 glds_src;
typedef __attribute__((address_space(3))) u32 glds_dst;

__global__ __launch_bounds__(256) void k_gemm128(
    const u16* __restrict__ xdir, const u16* __restrict__ xcvt,
    const int* __restrict__ flags, const u16* __restrict__ Bt,
    u16* __restrict__ C, int M, int K, int ldc) {
    const u16* A = flags[1] ? xdir : xcvt;
    __shared__ __align__(16) u16 As[128 * 32];
    __shared__ __align__(16) u16 Bs[128 * 32];
    int tid = threadIdx.x;
    int wave = tid >> 6, lane = tid & 63;
    int quad = lane >> 4, lrow = lane & 15;
    int wrow = (wave & 1) * 64, wcol = (wave >> 1) * 64;
    int row0 = blockIdx.x * 128;
    int n0 = blockIdx.y * 128;

    int lr = lane >> 2;
    int lc = (lane & 3) * 8;
    int ar = row0 + wave * 32 + lr;
    int br = n0 + wave * 32 + lr;
    u16* As_w = As + (wave * 32) * 32;
    u16* Bs_w = Bs + (wave * 32) * 32;

    f32x4 acc[4][4] = {};
    int kTiles = K >> 5;
    for (int kt = 0; kt < kTiles; ++kt) {
        int k0 = kt * 32;
        int a0 = imin(ar, M - 1);
        int a1 = imin(ar + 16, M - 1);
        const u16* ga0 = A + (size_t)a0 * K + k0 + lc;
        const u16* ga1 = A + (size_t)a1 * K + k0 + lc;
        const u16* gb0 = Bt + (size_t)br * K + k0 + lc;
        const u16* gb1 = Bt + (size_t)(br + 16) * K + k0 + lc;
        __builtin_amdgcn_global_load_lds((glds_src*)ga0, (glds_dst*)As_w, 16, 0, 0);
        __builtin_amdgcn_global_load_lds((glds_src*)ga1, (glds_dst*)(As_w + 16 * 32), 16, 0, 0);
        __builtin_amdgcn_global_load_lds((glds_src*)gb0, (glds_dst*)Bs_w, 16, 0, 0);
        __builtin_amdgcn_global_load_lds((glds_src*)gb1, (glds_dst*)(Bs_w + 16 * 32), 16, 0, 0);
        __syncthreads();
        bf16x8 af[4], bfr[4];
#pragma unroll
        for (int i = 0; i < 4; ++i)
            af[i] = *(const bf16x8*)(As + (wrow + i * 16 + lrow) * 32 + quad * 8);
#pragma unroll
        for (int j = 0; j < 4; ++j)
            bfr[j] = *(const bf16x8*)(Bs + (wcol + j * 16 + lrow) * 32 + quad * 8);
#pragma unroll
        for (int i = 0; i < 4; ++i)
#pragma unroll
            for (int j = 0; j < 4; ++j)
                acc[i][j] = __builtin_amdgcn_mfma_f32_16x16x32_bf16(af[i], bfr[j],
                                                                    acc[i][j], 0, 0, 0);
        __syncthreads();
    }
#pragma unroll
    for (int i = 0; i < 4; ++i)
#pragma unroll
        for (int j = 0; j < 4; ++j)
#pragma unroll
            for (int r = 0; r < 4; ++r) {
                int row = row0 + wrow + i * 16 + quad * 4 + r;
                int col = n0 + wcol + j * 16 + lrow;
                if (row < M) C[(size_t)row * ldc + col] = f2bf(acc[i][j][r]);
            }
}

// ---------------- GEMM2: 64x64 tile, fp32 out ----------------
__global__ __launch_bounds__(256) void k_gemm64(
    const u16* __restrict__ A, const u16* __restrict__ Bt, float* __restrict__ Cout,
    int M, int K, int Ncols, int ldc) {
    __shared__ __align__(16) u16 As[64 * 32];
    __shared__ __align__(16) u16 Bs[64 * 32];
    int tid = threadIdx.x;
    int wave = tid >> 6, lane = tid & 63;
    int quad = lane >> 4, lrow = lane & 15;
    int row0 = blockIdx.x * 64;
    int n0 = blockIdx.y * 64;
    int srow = tid >> 2;
    int skc = (tid & 3) * 8;

    f32x4 acc[4] = {};
    int kTiles = K >> 5;
    for (int kt = 0; kt < kTiles; ++kt) {
        int k0 = kt * 32;
        uint4 av = make_uint4(0, 0, 0, 0);
        int gr = row0 + srow;
        if (gr < M) av = *(const uint4*)(A + (size_t)gr * K + k0 + skc);
        uint4 bv = *(const uint4*)(Bt + (size_t)(n0 + srow) * K + k0 + skc);
        __syncthreads();
        *(uint4*)(As + srow * 32 + skc) = av;
        *(uint4*)(Bs + srow * 32 + skc) = bv;
        __syncthreads();
        bf16x8 af = *(const bf16x8*)(As + (wave * 16 + lrow) * 32 + quad * 8);
#pragma unroll
        for (int t = 0; t < 4; ++t) {
            bf16x8 bfr = *(const bf16x8*)(Bs + (t * 16 + lrow) * 32 + quad * 8);
            acc[t] = __builtin_amdgcn_mfma_f32_16x16x32_bf16(af, bfr, acc[t], 0, 0, 0);
        }
    }
#pragma unroll
    for (int t = 0; t < 4; ++t)
#pragma unroll
        for (int r = 0; r < 4; ++r) {
            int row = wave * 16 + quad * 4 + r;
            int col = t * 16 + lrow;
            int gr = row0 + row, gc = n0 + col;
            if (gr < M && gc < Ncols) Cout[(size_t)gr * ldc + gc] = acc[t][r];
        }
}

// ---------------- agg1: hagg = ReLU(Anorm*h + b1), bf16 in/out ----------------
__device__ __forceinline__ void accum8(float* acc, uint4 p, float w) {
    acc[0] += w * bf2f((u16)p.x); acc[1] += w * bf2f((u16)(p.x >> 16));
    acc[2] += w * bf2f((u16)p.y); acc[3] += w * bf2f((u16)(p.y >> 16));
    acc[4] += w * bf2f((u16)p.z); acc[5] += w * bf2f((u16)(p.z >> 16));
    acc[6] += w * bf2f((u16)p.w); acc[7] += w * bf2f((u16)(p.w >> 16));
}

__global__ __launch_bounds__(256) void k_agg1(
    const u16* __restrict__ h, const int* __restrict__ csr, const int* __restrict__ offs,
    const float* __restrict__ dinv, const float* __restrict__ b1f,
    u16* __restrict__ out, int n, int Etot) {
    int wave = threadIdx.x >> 6, lane = threadIdx.x & 63;
    int v = blockIdx.x * 4 + wave;
    if (v >= n) return;
    float dv = dinv[v];
    float wself = dv * dv;

    float acc[8];
    uint4 hs = *(const uint4*)(h + (size_t)v * C_HID + lane * 8);
    acc[0] = wself * bf2f((u16)hs.x); acc[1] = wself * bf2f((u16)(hs.x >> 16));
    acc[2] = wself * bf2f((u16)hs.y); acc[3] = wself * bf2f((u16)(hs.y >> 16));
    acc[4] = wself * bf2f((u16)hs.z); acc[5] = wself * bf2f((u16)(hs.z >> 16));
    acc[6] = wself * bf2f((u16)hs.w); acc[7] = wself * bf2f((u16)(hs.w >> 16));

    int e0 = imax(0, imin(offs[v], Etot));
    int e1 = imax(e0, imin(offs[v + 1], Etot));
    for (int base = e0; base < e1; base += 64) {
        int cnt = imin(64, e1 - base);
        int sreg = 0; float wreg = 0.f;
        if (lane < cnt) {
            u32 s = (u32)csr[base + lane];
            s = (s < (u32)n) ? s : 0u;
            sreg = (int)s;
            wreg = dv * dinv[s];
        }
        int j = 0;
        for (; j + 8 <= cnt; j += 8) {
            int ss[8]; float ww[8]; uint4 pp[8];
#pragma unroll
            for (int t = 0; t < 8; ++t) {
                ss[t] = __shfl(sreg, j + t);
                ww[t] = __shfl(wreg, j + t);
            }
#pragma unroll
            for (int t = 0; t < 8; ++t)
                pp[t] = *(const uint4*)(h + (size_t)ss[t] * C_HID + lane * 8);
#pragma unroll
            for (int t = 0; t < 8; ++t) accum8(acc, pp[t], ww[t]);
        }
        for (; j + 2 <= cnt; j += 2) {
            int s0 = __shfl(sreg, j), s1 = __shfl(sreg, j + 1);
            float w0 = __shfl(wreg, j), w1 = __shfl(wreg, j + 1);
            uint4 p0 = *(const uint4*)(h + (size_t)s0 * C_HID + lane * 8);
            uint4 p1 = *(const uint4*)(h + (size_t)s1 * C_HID + lane * 8);
            accum8(acc, p0, w0); accum8(acc, p1, w1);
        }
        for (; j < cnt; ++j) {
            int sj = __shfl(sreg, j);
            float wj = __shfl(wreg, j);
            uint4 pj = *(const uint4*)(h + (size_t)sj * C_HID + lane * 8);
            accum8(acc, pj, wj);
        }
    }

    float4 ba = *(const float4*)(b1f + lane * 8);
    float4 bb = *(const float4*)(b1f + lane * 8 + 4);
    float r0 = fmaxf(acc[0] + ba.x, 0.f), r1 = fmaxf(acc[1] + ba.y, 0.f);
    float r2 = fmaxf(acc[2] + ba.z, 0.f), r3 = fmaxf(acc[3] + ba.w, 0.f);
    float r4 = fmaxf(acc[4] + bb.x, 0.f), r5 = fmaxf(acc[5] + bb.y, 0.f);
    float r6 = fmaxf(acc[6] + bb.z, 0.f), r7 = fmaxf(acc[7] + bb.w, 0.f);
    uint4 o;
    o.x = (u32)f2bf(r0) | ((u32)f2bf(r1) << 16);
    o.y = (u32)f2bf(r2) | ((u32)f2bf(r3) << 16);
    o.z = (u32)f2bf(r4) | ((u32)f2bf(r5) << 16);
    o.w = (u32)f2bf(r6) | ((u32)f2bf(r7) << 16);
    *(uint4*)(out + (size_t)v * C_HID + lane * 8) = o;
}

// ---------------- agg2 + bias + log_softmax: 6 edges per wave-load ----------------
// lane = g*10 + f4 : g = edge slot (0..5; lanes 60..63 idle), f4 = float4 index
// over the 40 features. One float4 gather per active lane per 6-edge step.
__global__ __launch_bounds__(256) void k_agg2(
    const float* __restrict__ h2, const int* __restrict__ csr, const int* __restrict__ offs,
    const float* __restrict__ dinv, const float* __restrict__ b2f,
    const int* __restrict__ flags, void* __restrict__ out, int n, int Etot) {
    int wave = threadIdx.x >> 6, lane = threadIdx.x & 63;
    int v = blockIdx.x * 4 + wave;
    if (v >= n) return;
    float dv = dinv[v];

    int g = lane / 10;            // 0..6
    int f4 = lane - g * 10;       // 0..9
    bool active = (g < 6);

    float4 acc = make_float4(0.f, 0.f, 0.f, 0.f);
    if (g == 0) {                  // self term handled by group 0
        float4 p = *(const float4*)(h2 + (size_t)v * C_OUT + f4 * 4);
        float w = dv * dv;
        acc.x = w * p.x; acc.y = w * p.y; acc.z = w * p.z; acc.w = w * p.w;
    }

    int e0 = imax(0, imin(offs[v], Etot));
    int e1 = imax(e0, imin(offs[v + 1], Etot));
    for (int base = e0; base < e1; base += 64) {
        int cnt = imin(64, e1 - base);
        int sreg = 0; float wreg = 0.f;
        if (lane < cnt) {
            u32 s = (u32)csr[base + lane];
            s = (s < (u32)n) ? s : 0u;
            sreg = (int)s;
            wreg = dv * dinv[s];
        }
        for (int j = 0; j < cnt; j += 6) {
            int idx = imin(j + g, cnt - 1);
            int sj = __shfl(sreg, idx);
            float wj = __shfl(wreg, idx);
            if (!active || j + g >= cnt) wj = 0.f;
            if (active) {
                float4 p = *(const float4*)(h2 + (size_t)sj * C_OUT + f4 * 4);
                acc.x += wj * p.x; acc.y += wj * p.y;
                acc.z += wj * p.z; acc.w += wj * p.w;
            }
        }
    }

    // reduce the 6 edge-slot groups (lanes g*10+f4) down to lanes 0..9
    float4 t;
    t.x = __shfl(acc.x, lane + 30); t.y = __shfl(acc.y, lane + 30);
    t.z = __shfl(acc.z, lane + 30); t.w = __shfl(acc.w, lane + 30);
    if (lane < 30) { acc.x += t.x; acc.y += t.y; acc.z += t.z; acc.w += t.w; }
    float4 t1, t2;
    t1.x = __shfl(acc.x, lane + 10); t1.y = __shfl(acc.y, lane + 10);
    t1.z = __shfl(acc.z, lane + 10); t1.w = __shfl(acc.w, lane + 10);
    t2.x = __shfl(acc.x, lane + 20); t2.y = __shfl(acc.y, lane + 20);
    t2.z = __shfl(acc.z, lane + 20); t2.w = __shfl(acc.w, lane + 20);
    if (lane < 10) {
        acc.x += t1.x + t2.x; acc.y += t1.y + t2.y;
        acc.z += t1.z + t2.z; acc.w += t1.w + t2.w;
        acc.x += b2f[f4 * 4 + 0]; acc.y += b2f[f4 * 4 + 1];
        acc.z += b2f[f4 * 4 + 2]; acc.w += b2f[f4 * 4 + 3];
    }

    // log_softmax over the 40 features (held as float4 in lanes 0..9)
    float m = -1e30f;
    if (lane < 10) m = fmaxf(fmaxf(acc.x, acc.y), fmaxf(acc.z, acc.w));
    for (int off = 32; off > 0; off >>= 1) m = fmaxf(m, __shfl_xor(m, off));
    float s = 0.f;
    if (lane < 10)
        s = expf(acc.x - m) + expf(acc.y - m) + expf(acc.z - m) + expf(acc.w - m);
    for (int off = 32; off > 0; off >>= 1) s += __shfl_xor(s, off);
    if (lane < 10) {
        float ls = m + logf(s);
        if (flags[1]) {
            ushort4 o;
            o.x = f2bf(acc.x - ls); o.y = f2bf(acc.y - ls);
            o.z = f2bf(acc.z - ls); o.w = f2bf(acc.w - ls);
            *(ushort4*)((u16*)out + (size_t)v * C_OUT + f4 * 4) = o;
        } else {
            float4 o = make_float4(acc.x - ls, acc.y - ls, acc.z - ls, acc.w - ls);
            *(float4*)((float*)out + (size_t)v * C_OUT + f4 * 4) = o;
        }
    }
}

// ---------------- launch ----------------

extern "C" void kernel_launch(void* const* d_in, const int* in_sizes, int n_in,
                              void* d_out, int out_size, void* d_ws, size_t ws_size,
                              hipStream_t stream) {
    const void* x = d_in[0];
    const int* ei = (const int*)d_in[1];
    const void* W1 = d_in[2];
    const void* b1 = d_in[3];
    const void* W2 = d_in[4];
    const void* b2 = d_in[5];

    const int N = out_size / C_OUT;
    const int Mx = in_sizes[0] / C_IN;
    const int M = (N < Mx) ? N : Mx;
    const int ECAP = in_sizes[1];
    const int E = ECAP / 2;

    char* p = (char*)d_ws;
    size_t used = 0;
    auto carve = [&](size_t bytes) -> void* {
        void* r = (void*)p;
        size_t b = (bytes + 255) & ~(size_t)255;
        p += b; used += b;
        return r;
    };
    int* flags = (int*)carve(256);
    int* deg = (int*)carve((size_t)N * 4);
    int* cursor = (int*)carve((size_t)N * 4);
    float* dinv = (float*)carve((size_t)N * 4);
    int* offs = (int*)carve((size_t)(N + 1) * 4);
    int* bsum = (int*)carve(8192);
    int* csr = (int*)carve((size_t)E * 4);
    u16* w1t = (u16*)carve((size_t)C_HID * C_IN * 2);
    u16* w2t = (u16*)carve((size_t)64 * C_HID * 2);
    float* b1f = (float*)carve(C_HID * 4);
    float* b2f = (float*)carve(256);
    u16* bufA = (u16*)carve((size_t)N * C_HID * 2);   // xcvt (fp32 case), then hagg
    u16* bufB = (u16*)carve((size_t)N * C_HID * 2);   // hbf, then h2 (fp32)
    if (used > ws_size) return;

    u16* xcvt = bufA;
    u16* hbf = bufB;
    u16* hagg = bufA;
    float* h2 = (float*)bufB;

    const int NB = (N + 255) / 256;
    const int EB = (E + 255) / 256;

    k_init<<<NB, 256, 0, stream>>>((const u32*)x, ei, flags, deg, cursor, N);
    k_deg<<<EB, 256, 0, stream>>>(ei, flags, deg, E, ECAP, N);
    k_scanA<<<NB, 256, 0, stream>>>(deg, bsum, dinv, N);
    k_scanB<<<1, 64, 0, stream>>>(bsum, NB, offs, N);
    k_scanC<<<NB, 256, 0, stream>>>(deg, bsum, offs, N);
    k_sort<<<EB, 256, 0, stream>>>(ei, flags, offs, cursor, csr, E, ECAP, N);

    k_prep<<<2048, 256, 0, stream>>>(x, W1, b1, W2, b2, flags, w1t, w2t,
                                     b1f, b2f, xcvt, M * C_IN);

    dim3 g1((M + 127) / 128, C_HID / 128);
    k_gemm128<<<g1, 256, 0, stream>>>((const u16*)x, xcvt, flags, w1t, hbf,
                                      M, C_IN, C_HID);

    k_agg1<<<(N + 3) / 4, 256, 0, stream>>>(hbf, csr, offs, dinv, b1f, hagg, N, E);

    dim3 g2((N + 63) / 64, 1);
    k_gemm64<<<g2, 256, 0, stream>>>(hagg, w2t, h2, N, C_HID, C_OUT, C_OUT);

    k_agg2<<<(N + 3) / 4, 256, 0, stream>>>(h2, csr, offs, dinv, b2f, flags, d_out, N, E);
}

// Round 10
// 466.596 us; speedup vs baseline: 1.4372x; 1.0559x over previous
//
#include <hip/hip_runtime.h>

// GCN 2-layer forward on gfx950.
// R10: gemm128 K-tile 32->64 via split-half LDS buffers (half the barriers,
//      same conflict-free 64B-row-stride + glds-contiguous layout);
//      k_scanB parallelized (was 196 serial dependent RMWs on one thread).

typedef unsigned int u32;
typedef unsigned short u16;
typedef __bf16 bf16x8 __attribute__((ext_vector_type(8)));
typedef float f32x4 __attribute__((ext_vector_type(4)));

#define C_IN 512
#define C_HID 512
#define C_OUT 40

__device__ __forceinline__ float bf2f(u16 u) {
    u32 x = ((u32)u) << 16;
    return __builtin_bit_cast(float, x);
}
__device__ __forceinline__ u16 f2bf(float f) {
    u32 x = __builtin_bit_cast(u32, f);
    x += 0x7fffu + ((x >> 16) & 1u);   // RNE
    return (u16)(x >> 16);
}
__host__ __device__ __forceinline__ int imin(int a, int b) { return a < b ? a : b; }
__host__ __device__ __forceinline__ int imax(int a, int b) { return a > b ? a : b; }

// ---------------- init + dtype detect (fused) ----------------
__global__ void k_init(const u32* __restrict__ x32, const int* __restrict__ ei,
                       int* flags, int* deg, int* cursor, int n) {
    if (blockIdx.x == 0 && threadIdx.x < 64) {
        int lane = threadIdx.x;
        int z = (ei[2 * lane + 1] == 0) ? 1 : 0;
        u32 e = (x32[lane] >> 7) & 0xff;
        int v = (e >= 110 && e <= 133) ? 1 : 0;
        unsigned long long bz = __ballot(z);
        unsigned long long bv = __ballot(v);
        if (lane == 0) {
            flags[0] = (__popcll(bz) == 64) ? 2 : 1;   // int32 step per element
            flags[1] = (__popcll(bv) >= 48) ? 1 : 0;   // floats bf16-packed?
        }
    }
    int i = blockIdx.x * 256 + threadIdx.x;
    if (i < n) { deg[i] = 1; cursor[i] = 0; }          // self-loop
}

__global__ void k_deg(const int* __restrict__ ei, const int* __restrict__ flags,
                      int* deg, int E, int ecap, int n) {
    int e = blockIdx.x * 256 + threadIdx.x;
    if (e >= E) return;
    int st = flags[0];
    int cap = ecap * st - 1;
    u32 d = (u32)ei[imin((E + e) * st, cap)];
    if (d < (u32)n) atomicAdd(&deg[d], 1);
}

// block sums of (deg-1) + dinv (fused)
__global__ void k_scanA(const int* __restrict__ deg, int* bsum, float* dinv, int n) {
    __shared__ int sh[256];
    int i = blockIdx.x * 256 + threadIdx.x;
    int dv = (i < n) ? deg[i] : 1;
    if (i < n) dinv[i] = rsqrtf((float)imax(dv, 1));
    sh[threadIdx.x] = (i < n) ? dv - 1 : 0;
    __syncthreads();
    for (int d = 128; d > 0; d >>= 1) {
        if (threadIdx.x < d) sh[threadIdx.x] += sh[threadIdx.x + d];
        __syncthreads();
    }
    if (threadIdx.x == 0) bsum[blockIdx.x] = sh[0];
}

// parallel exclusive scan of bsum (one 256-thread block, chunked with carry)
__global__ void k_scanB(int* bsum, int nb, int* offs, int n) {
    __shared__ int sh[256];
    int t = threadIdx.x;
    int carry = 0;
    for (int base = 0; base < nb; base += 256) {
        int i = base + t;
        int v = (i < nb) ? bsum[i] : 0;
        sh[t] = v;
        __syncthreads();
        for (int d = 1; d < 256; d <<= 1) {
            int add = (t >= d) ? sh[t - d] : 0;
            __syncthreads();
            sh[t] += add;
            __syncthreads();
        }
        if (i < nb) bsum[i] = carry + sh[t] - v;   // exclusive
        int tot = sh[255];
        __syncthreads();
        carry += tot;
    }
    if (t == 0) offs[n] = carry;
}

__global__ void k_scanC(const int* __restrict__ deg, const int* __restrict__ bsum,
                        int* offs, int n) {
    __shared__ int sh[256];
    int t = threadIdx.x;
    int i = blockIdx.x * 256 + t;
    int v = (i < n) ? deg[i] - 1 : 0;
    sh[t] = v;
    __syncthreads();
    for (int d = 1; d < 256; d <<= 1) {
        int add = (t >= d) ? sh[t - d] : 0;
        __syncthreads();
        sh[t] += add;
        __syncthreads();
    }
    if (i < n) offs[i] = bsum[blockIdx.x] + sh[t] - v;
}

__global__ void k_sort(const int* __restrict__ ei, const int* __restrict__ flags,
                       const int* __restrict__ offs, int* cursor, int* csr,
                       int E, int ecap, int n) {
    int e = blockIdx.x * 256 + threadIdx.x;
    if (e >= E) return;
    int st = flags[0];
    int cap = ecap * st - 1;
    u32 d = (u32)ei[imin((E + e) * st, cap)];
    u32 s = (u32)ei[imin(e * st, cap)];
    if (d < (u32)n && s < (u32)n) {
        int pos = offs[d] + atomicAdd(&cursor[(int)d], 1);
        if ((u32)pos < (u32)E) csr[pos] = (int)s;
    }
}

// ---------------- fused prep: w1t + w2t + bias + (convx if fp32) ----------------
__device__ __forceinline__ float ldf(const void* p, int i, int isbf) {
    return isbf ? bf2f(((const u16*)p)[i]) : ((const float*)p)[i];
}

__global__ __launch_bounds__(256) void k_prep(
    const void* __restrict__ x, const void* __restrict__ W1, const void* __restrict__ b1,
    const void* __restrict__ W2, const void* __restrict__ b2,
    const int* __restrict__ flags, u16* __restrict__ w1t, u16* __restrict__ w2t,
    float* __restrict__ b1f, float* __restrict__ b2f, u16* __restrict__ xcvt,
    int nx) {
    int isbf = flags[1];
    int stride = gridDim.x * 256;
    int i0 = blockIdx.x * 256 + threadIdx.x;
    for (int i = i0; i < 512 * 512; i += stride) {
        int n = i >> 9, k = i & 511;
        w1t[n * 512 + k] = f2bf(ldf(W1, k * 512 + n, isbf));
    }
    for (int i = i0; i < 64 * 512; i += stride) {
        int n = i >> 9, k = i & 511;
        w2t[i] = (n < C_OUT) ? f2bf(ldf(W2, k * C_OUT + n, isbf)) : (u16)0;
    }
    if (i0 < C_HID) b1f[i0] = ldf(b1, i0, isbf);
    if (i0 < C_OUT) b2f[i0] = ldf(b2, i0, isbf);
    if (!isbf) {
        for (int i = i0; i < nx; i += stride)
            xcvt[i] = f2bf(((const float*)x)[i]);
    }
}

// ---------------- GEMM1: 128x128 tile, BK=64, split-half LDS, glds staging -----------
// Each K-iteration stages a 128x64 A-tile and B-tile as two 128x32 halves
// (row stride 64B: conflict-free ds_read_b128, glds-contiguous 16-row groups).
// Layouts (learn_hip m89/m91/m120): A frag A[m=lane&15][k=quad*8+j];
// B frag == Bt[n=lane&15][k]; C/D row=quad*4+reg, col=lane&15.
typedef __attribute__((address_space(1))) const u32 glds_src;
typedef __attribute__((address_space(3))) u32 glds_dst;

__global__ __launch_bounds__(256) void k_gemm128(
    const u16* __restrict__ xdir, const u16* __restrict__ xcvt,
    const int* __restrict__ flags, const u16* __restrict__ Bt,
    u16* __restrict__ C, int M, int K, int ldc) {
    const u16* A = flags[1] ? xdir : xcvt;
    __shared__ __align__(16) u16 As0[128 * 32], As1[128 * 32];
    __shared__ __align__(16) u16 Bs0[128 * 32], Bs1[128 * 32];
    int tid = threadIdx.x;
    int wave = tid >> 6, lane = tid & 63;
    int quad = lane >> 4, lrow = lane & 15;
    int wrow = (wave & 1) * 64, wcol = (wave >> 1) * 64;
    int row0 = blockIdx.x * 128;
    int n0 = blockIdx.y * 128;

    int lr = lane >> 2;           // 0..15 row within 16-row staging group
    int lc = (lane & 3) * 8;      // element col offset 0,8,16,24 (16B per lane)
    int ar = row0 + wave * 32 + lr;
    int br = n0 + wave * 32 + lr;
    u16* As0_w = As0 + (wave * 32) * 32;
    u16* As1_w = As1 + (wave * 32) * 32;
    u16* Bs0_w = Bs0 + (wave * 32) * 32;
    u16* Bs1_w = Bs1 + (wave * 32) * 32;

    f32x4 acc[4][4] = {};
    int kTiles = K >> 6;   // BK=64
    for (int kt = 0; kt < kTiles; ++kt) {
        int k0 = kt * 64;
        int a0 = imin(ar, M - 1);
        int a1 = imin(ar + 16, M - 1);
        const u16* gA0 = A + (size_t)a0 * K + k0 + lc;
        const u16* gA1 = A + (size_t)a1 * K + k0 + lc;
        const u16* gB0 = Bt + (size_t)br * K + k0 + lc;
        const u16* gB1 = Bt + (size_t)(br + 16) * K + k0 + lc;
        __builtin_amdgcn_global_load_lds((glds_src*)gA0, (glds_dst*)As0_w, 16, 0, 0);
        __builtin_amdgcn_global_load_lds((glds_src*)gA1, (glds_dst*)(As0_w + 16 * 32), 16, 0, 0);
        __builtin_amdgcn_global_load_lds((glds_src*)(gA0 + 32), (glds_dst*)As1_w, 16, 0, 0);
        __builtin_amdgcn_global_load_lds((glds_src*)(gA1 + 32), (glds_dst*)(As1_w + 16 * 32), 16, 0, 0);
        __builtin_amdgcn_global_load_lds((glds_src*)gB0, (glds_dst*)Bs0_w, 16, 0, 0);
        __builtin_amdgcn_global_load_lds((glds_src*)gB1, (glds_dst*)(Bs0_w + 16 * 32), 16, 0, 0);
        __builtin_amdgcn_global_load_lds((glds_src*)(gB0 + 32), (glds_dst*)Bs1_w, 16, 0, 0);
        __builtin_amdgcn_global_load_lds((glds_src*)(gB1 + 32), (glds_dst*)(Bs1_w + 16 * 32), 16, 0, 0);
        __syncthreads();
#pragma unroll
        for (int ko = 0; ko < 2; ++ko) {
            const u16* Asrc = ko ? As1 : As0;
            const u16* Bsrc = ko ? Bs1 : Bs0;
            bf16x8 af[4], bfr[4];
#pragma unroll
            for (int i = 0; i < 4; ++i)
                af[i] = *(const bf16x8*)(Asrc + (wrow + i * 16 + lrow) * 32 + quad * 8);
#pragma unroll
            for (int j = 0; j < 4; ++j)
                bfr[j] = *(const bf16x8*)(Bsrc + (wcol + j * 16 + lrow) * 32 + quad * 8);
#pragma unroll
            for (int i = 0; i < 4; ++i)
#pragma unroll
                for (int j = 0; j < 4; ++j)
                    acc[i][j] = __builtin_amdgcn_mfma_f32_16x16x32_bf16(af[i], bfr[j],
                                                                        acc[i][j], 0, 0, 0);
        }
        __syncthreads();
    }
#pragma unroll
    for (int i = 0; i < 4; ++i)
#pragma unroll
        for (int j = 0; j < 4; ++j)
#pragma unroll
            for (int r = 0; r < 4; ++r) {
                int row = row0 + wrow + i * 16 + quad * 4 + r;
                int col = n0 + wcol + j * 16 + lrow;
                if (row < M) C[(size_t)row * ldc + col] = f2bf(acc[i][j][r]);
            }
}

// ---------------- GEMM2: 64x64 tile, fp32 out ----------------
__global__ __launch_bounds__(256) void k_gemm64(
    const u16* __restrict__ A, const u16* __restrict__ Bt, float* __restrict__ Cout,
    int M, int K, int Ncols, int ldc) {
    __shared__ __align__(16) u16 As[64 * 32];
    __shared__ __align__(16) u16 Bs[64 * 32];
    int tid = threadIdx.x;
    int wave = tid >> 6, lane = tid & 63;
    int quad = lane >> 4, lrow = lane & 15;
    int row0 = blockIdx.x * 64;
    int n0 = blockIdx.y * 64;
    int srow = tid >> 2;
    int skc = (tid & 3) * 8;

    f32x4 acc[4] = {};
    int kTiles = K >> 5;
    for (int kt = 0; kt < kTiles; ++kt) {
        int k0 = kt * 32;
        uint4 av = make_uint4(0, 0, 0, 0);
        int gr = row0 + srow;
        if (gr < M) av = *(const uint4*)(A + (size_t)gr * K + k0 + skc);
        uint4 bv = *(const uint4*)(Bt + (size_t)(n0 + srow) * K + k0 + skc);
        __syncthreads();
        *(uint4*)(As + srow * 32 + skc) = av;
        *(uint4*)(Bs + srow * 32 + skc) = bv;
        __syncthreads();
        bf16x8 af = *(const bf16x8*)(As + (wave * 16 + lrow) * 32 + quad * 8);
#pragma unroll
        for (int t = 0; t < 4; ++t) {
            bf16x8 bfr = *(const bf16x8*)(Bs + (t * 16 + lrow) * 32 + quad * 8);
            acc[t] = __builtin_amdgcn_mfma_f32_16x16x32_bf16(af, bfr, acc[t], 0, 0, 0);
        }
    }
#pragma unroll
    for (int t = 0; t < 4; ++t)
#pragma unroll
        for (int r = 0; r < 4; ++r) {
            int row = wave * 16 + quad * 4 + r;
            int col = t * 16 + lrow;
            int gr = row0 + row, gc = n0 + col;
            if (gr < M && gc < Ncols) Cout[(size_t)gr * ldc + gc] = acc[t][r];
        }
}

// ---------------- agg1: hagg = ReLU(Anorm*h + b1), bf16 in/out ----------------
__device__ __forceinline__ void accum8(float* acc, uint4 p, float w) {
    acc[0] += w * bf2f((u16)p.x); acc[1] += w * bf2f((u16)(p.x >> 16));
    acc[2] += w * bf2f((u16)p.y); acc[3] += w * bf2f((u16)(p.y >> 16));
    acc[4] += w * bf2f((u16)p.z); acc[5] += w * bf2f((u16)(p.z >> 16));
    acc[6] += w * bf2f((u16)p.w); acc[7] += w * bf2f((u16)(p.w >> 16));
}

__global__ __launch_bounds__(256) void k_agg1(
    const u16* __restrict__ h, const int* __restrict__ csr, const int* __restrict__ offs,
    const float* __restrict__ dinv, const float* __restrict__ b1f,
    u16* __restrict__ out, int n, int Etot) {
    int wave = threadIdx.x >> 6, lane = threadIdx.x & 63;
    int v = blockIdx.x * 4 + wave;
    if (v >= n) return;
    float dv = dinv[v];
    float wself = dv * dv;

    float acc[8];
    uint4 hs = *(const uint4*)(h + (size_t)v * C_HID + lane * 8);
    acc[0] = wself * bf2f((u16)hs.x); acc[1] = wself * bf2f((u16)(hs.x >> 16));
    acc[2] = wself * bf2f((u16)hs.y); acc[3] = wself * bf2f((u16)(hs.y >> 16));
    acc[4] = wself * bf2f((u16)hs.z); acc[5] = wself * bf2f((u16)(hs.z >> 16));
    acc[6] = wself * bf2f((u16)hs.w); acc[7] = wself * bf2f((u16)(hs.w >> 16));

    int e0 = imax(0, imin(offs[v], Etot));
    int e1 = imax(e0, imin(offs[v + 1], Etot));
    for (int base = e0; base < e1; base += 64) {
        int cnt = imin(64, e1 - base);
        int sreg = 0; float wreg = 0.f;
        if (lane < cnt) {
            u32 s = (u32)csr[base + lane];
            s = (s < (u32)n) ? s : 0u;
            sreg = (int)s;
            wreg = dv * dinv[s];
        }
        int j = 0;
        for (; j + 8 <= cnt; j += 8) {
            int ss[8]; float ww[8]; uint4 pp[8];
#pragma unroll
            for (int t = 0; t < 8; ++t) {
                ss[t] = __shfl(sreg, j + t);
                ww[t] = __shfl(wreg, j + t);
            }
#pragma unroll
            for (int t = 0; t < 8; ++t)
                pp[t] = *(const uint4*)(h + (size_t)ss[t] * C_HID + lane * 8);
#pragma unroll
            for (int t = 0; t < 8; ++t) accum8(acc, pp[t], ww[t]);
        }
        for (; j + 2 <= cnt; j += 2) {
            int s0 = __shfl(sreg, j), s1 = __shfl(sreg, j + 1);
            float w0 = __shfl(wreg, j), w1 = __shfl(wreg, j + 1);
            uint4 p0 = *(const uint4*)(h + (size_t)s0 * C_HID + lane * 8);
            uint4 p1 = *(const uint4*)(h + (size_t)s1 * C_HID + lane * 8);
            accum8(acc, p0, w0); accum8(acc, p1, w1);
        }
        for (; j < cnt; ++j) {
            int sj = __shfl(sreg, j);
            float wj = __shfl(wreg, j);
            uint4 pj = *(const uint4*)(h + (size_t)sj * C_HID + lane * 8);
            accum8(acc, pj, wj);
        }
    }

    float4 ba = *(const float4*)(b1f + lane * 8);
    float4 bb = *(const float4*)(b1f + lane * 8 + 4);
    float r0 = fmaxf(acc[0] + ba.x, 0.f), r1 = fmaxf(acc[1] + ba.y, 0.f);
    float r2 = fmaxf(acc[2] + ba.z, 0.f), r3 = fmaxf(acc[3] + ba.w, 0.f);
    float r4 = fmaxf(acc[4] + bb.x, 0.f), r5 = fmaxf(acc[5] + bb.y, 0.f);
    float r6 = fmaxf(acc[6] + bb.z, 0.f), r7 = fmaxf(acc[7] + bb.w, 0.f);
    uint4 o;
    o.x = (u32)f2bf(r0) | ((u32)f2bf(r1) << 16);
    o.y = (u32)f2bf(r2) | ((u32)f2bf(r3) << 16);
    o.z = (u32)f2bf(r4) | ((u32)f2bf(r5) << 16);
    o.w = (u32)f2bf(r6) | ((u32)f2bf(r7) << 16);
    *(uint4*)(out + (size_t)v * C_HID + lane * 8) = o;
}

// ---------------- agg2 + bias + log_softmax: 6 edges per wave-load ----------------
__global__ __launch_bounds__(256) void k_agg2(
    const float* __restrict__ h2, const int* __restrict__ csr, const int* __restrict__ offs,
    const float* __restrict__ dinv, const float* __restrict__ b2f,
    const int* __restrict__ flags, void* __restrict__ out, int n, int Etot) {
    int wave = threadIdx.x >> 6, lane = threadIdx.x & 63;
    int v = blockIdx.x * 4 + wave;
    if (v >= n) return;
    float dv = dinv[v];

    int g = lane / 10;            // 0..6
    int f4 = lane - g * 10;       // 0..9
    bool active = (g < 6);

    float4 acc = make_float4(0.f, 0.f, 0.f, 0.f);
    if (g == 0) {
        float4 p = *(const float4*)(h2 + (size_t)v * C_OUT + f4 * 4);
        float w = dv * dv;
        acc.x = w * p.x; acc.y = w * p.y; acc.z = w * p.z; acc.w = w * p.w;
    }

    int e0 = imax(0, imin(offs[v], Etot));
    int e1 = imax(e0, imin(offs[v + 1], Etot));
    for (int base = e0; base < e1; base += 64) {
        int cnt = imin(64, e1 - base);
        int sreg = 0; float wreg = 0.f;
        if (lane < cnt) {
            u32 s = (u32)csr[base + lane];
            s = (s < (u32)n) ? s : 0u;
            sreg = (int)s;
            wreg = dv * dinv[s];
        }
        for (int j = 0; j < cnt; j += 6) {
            int idx = imin(j + g, cnt - 1);
            int sj = __shfl(sreg, idx);
            float wj = __shfl(wreg, idx);
            if (!active || j + g >= cnt) wj = 0.f;
            if (active) {
                float4 p = *(const float4*)(h2 + (size_t)sj * C_OUT + f4 * 4);
                acc.x += wj * p.x; acc.y += wj * p.y;
                acc.z += wj * p.z; acc.w += wj * p.w;
            }
        }
    }

    float4 t;
    t.x = __shfl(acc.x, lane + 30); t.y = __shfl(acc.y, lane + 30);
    t.z = __shfl(acc.z, lane + 30); t.w = __shfl(acc.w, lane + 30);
    if (lane < 30) { acc.x += t.x; acc.y += t.y; acc.z += t.z; acc.w += t.w; }
    float4 t1, t2;
    t1.x = __shfl(acc.x, lane + 10); t1.y = __shfl(acc.y, lane + 10);
    t1.z = __shfl(acc.z, lane + 10); t1.w = __shfl(acc.w, lane + 10);
    t2.x = __shfl(acc.x, lane + 20); t2.y = __shfl(acc.y, lane + 20);
    t2.z = __shfl(acc.z, lane + 20); t2.w = __shfl(acc.w, lane + 20);
    if (lane < 10) {
        acc.x += t1.x + t2.x; acc.y += t1.y + t2.y;
        acc.z += t1.z + t2.z; acc.w += t1.w + t2.w;
        acc.x += b2f[f4 * 4 + 0]; acc.y += b2f[f4 * 4 + 1];
        acc.z += b2f[f4 * 4 + 2]; acc.w += b2f[f4 * 4 + 3];
    }

    float m = -1e30f;
    if (lane < 10) m = fmaxf(fmaxf(acc.x, acc.y), fmaxf(acc.z, acc.w));
    for (int off = 32; off > 0; off >>= 1) m = fmaxf(m, __shfl_xor(m, off));
    float s = 0.f;
    if (lane < 10)
        s = expf(acc.x - m) + expf(acc.y - m) + expf(acc.z - m) + expf(acc.w - m);
    for (int off = 32; off > 0; off >>= 1) s += __shfl_xor(s, off);
    if (lane < 10) {
        float ls = m + logf(s);
        if (flags[1]) {
            ushort4 o;
            o.x = f2bf(acc.x - ls); o.y = f2bf(acc.y - ls);
            o.z = f2bf(acc.z - ls); o.w = f2bf(acc.w - ls);
            *(ushort4*)((u16*)out + (size_t)v * C_OUT + f4 * 4) = o;
        } else {
            float4 o = make_float4(acc.x - ls, acc.y - ls, acc.z - ls, acc.w - ls);
            *(float4*)((float*)out + (size_t)v * C_OUT + f4 * 4) = o;
        }
    }
}

// ---------------- launch ----------------

extern "C" void kernel_launch(void* const* d_in, const int* in_sizes, int n_in,
                              void* d_out, int out_size, void* d_ws, size_t ws_size,
                              hipStream_t stream) {
    const void* x = d_in[0];
    const int* ei = (const int*)d_in[1];
    const void* W1 = d_in[2];
    const void* b1 = d_in[3];
    const void* W2 = d_in[4];
    const void* b2 = d_in[5];

    const int N = out_size / C_OUT;
    const int Mx = in_sizes[0] / C_IN;
    const int M = (N < Mx) ? N : Mx;
    const int ECAP = in_sizes[1];
    const int E = ECAP / 2;

    char* p = (char*)d_ws;
    size_t used = 0;
    auto carve = [&](size_t bytes) -> void* {
        void* r = (void*)p;
        size_t b = (bytes + 255) & ~(size_t)255;
        p += b; used += b;
        return r;
    };
    int* flags = (int*)carve(256);
    int* deg = (int*)carve((size_t)N * 4);
    int* cursor = (int*)carve((size_t)N * 4);
    float* dinv = (float*)carve((size_t)N * 4);
    int* offs = (int*)carve((size_t)(N + 1) * 4);
    int* bsum = (int*)carve(8192);
    int* csr = (int*)carve((size_t)E * 4);
    u16* w1t = (u16*)carve((size_t)C_HID * C_IN * 2);
    u16* w2t = (u16*)carve((size_t)64 * C_HID * 2);
    float* b1f = (float*)carve(C_HID * 4);
    float* b2f = (float*)carve(256);
    u16* bufA = (u16*)carve((size_t)N * C_HID * 2);   // xcvt (fp32 case), then hagg
    u16* bufB = (u16*)carve((size_t)N * C_HID * 2);   // hbf, then h2 (fp32)
    if (used > ws_size) return;

    u16* xcvt = bufA;
    u16* hbf = bufB;
    u16* hagg = bufA;
    float* h2 = (float*)bufB;

    const int NB = (N + 255) / 256;
    const int EB = (E + 255) / 256;

    k_init<<<NB, 256, 0, stream>>>((const u32*)x, ei, flags, deg, cursor, N);
    k_deg<<<EB, 256, 0, stream>>>(ei, flags, deg, E, ECAP, N);
    k_scanA<<<NB, 256, 0, stream>>>(deg, bsum, dinv, N);
    k_scanB<<<1, 256, 0, stream>>>(bsum, NB, offs, N);
    k_scanC<<<NB, 256, 0, stream>>>(deg, bsum, offs, N);
    k_sort<<<EB, 256, 0, stream>>>(ei, flags, offs, cursor, csr, E, ECAP, N);

    k_prep<<<2048, 256, 0, stream>>>(x, W1, b1, W2, b2, flags, w1t, w2t,
                                     b1f, b2f, xcvt, M * C_IN);

    dim3 g1((M + 127) / 128, C_HID / 128);
    k_gemm128<<<g1, 256, 0, stream>>>((const u16*)x, xcvt, flags, w1t, hbf,
                                      M, C_IN, C_HID);

    k_agg1<<<(N + 3) / 4, 256, 0, stream>>>(hbf, csr, offs, dinv, b1f, hagg, N, E);

    dim3 g2((N + 63) / 64, 1);
    k_gemm64<<<g2, 256, 0, stream>>>(hagg, w2t, h2, N, C_HID, C_OUT, C_OUT);

    k_agg2<<<(N + 3) / 4, 256, 0, stream>>>(h2, csr, offs, dinv, b2f, flags, d_out, N, E);
}